// Round 17
// baseline (256.579 us; speedup 1.0000x reference)
//
#include <hip/hip_runtime.h>

#define NN 100000
#define ENUM 25000
#define NNZ_C 200000
// D = 128, H = 4, F = 128, Wlin: [128,512]
// Aggregate-then-transform, with the node-side aggregation FUSED into the final GEMM:
//   aggX[e,(d,h)] = (1/8) sum_k alpha[k,h] X[row_k,d]            (bf16, [EN][512])
//   Xres = [ (0.25/Dn_r) sum_p alphag[p,h] aggX[c_p,:] ] @ Wbig + bias   (K=512)
// E-path: agg = B^-1 A^T X ; Eres = agg@Wn + E@We + (bn+be) + E.
// Weights PRE-SWIZZLED in global (pos ^ ((row&7)<<3)) -> linear global_load_lds DMA.

typedef __attribute__((ext_vector_type(8))) short bf16x8;
typedef __attribute__((ext_vector_type(4))) float f32x4;

__device__ __forceinline__ float blo(unsigned u) { return __uint_as_float(u << 16); }
__device__ __forceinline__ float bhi(unsigned u) { return __uint_as_float(u & 0xFFFF0000u); }
__device__ __forceinline__ unsigned short f2bf(float x) {
    unsigned u = __float_as_uint(x);
    unsigned r = (u + 0x7fff + ((u >> 16) & 1)) >> 16;   // RNE
    return (unsigned short)r;
}
__device__ __forceinline__ unsigned pack2(float a, float b) {
    return (unsigned)f2bf(a) | ((unsigned)f2bf(b) << 16);
}
__device__ __forceinline__ void gload_lds16(const unsigned short* g, unsigned short* l) {
    __builtin_amdgcn_global_load_lds(
        (const __attribute__((address_space(1))) void*)g,
        (__attribute__((address_space(3))) void*)l, 16, 0, 0);
}

// -------- W[128][NC] f32 -> Wt bf16, row c, stored at swizzled position --------
__global__ __launch_bounds__(256) void wtr_k(
    const float* __restrict__ W, unsigned short* __restrict__ Wt, int NC)
{
    const int t = blockIdx.x * 256 + threadIdx.x;
    if (t >= 128 * NC) return;
    const int c = t % NC, k = t / NC;
    const size_t pos = ((size_t)c * 128 + k) ^ ((c & 7) << 3);
    Wt[pos] = f2bf(W[t]);
}

// -------- Wlin[128][512] -> WbigT: 4 chunks of [128 cols][128 kk], swizzled ----
// kk = d*4+h ; WbigT[c][kk] = Wlin[d][h*128+c]
__global__ __launch_bounds__(256) void wtr_big_k(
    const float* __restrict__ Wlin, unsigned short* __restrict__ WbigT)
{
    const int t = blockIdx.x * 256 + threadIdx.x;
    if (t >= 128 * 512) return;
    const int d = t >> 9, c512 = t & 511;
    const int h = c512 >> 7, f = c512 & 127;
    const int kk = d * 4 + h;
    const int kc = kk >> 7, dd = kk & 127;
    const size_t pos = (size_t)kc * 16384 + (((size_t)f * 128 + dd) ^ ((f & 7) << 3));
    WbigT[pos] = f2bf(Wlin[t]);
}

// -------- A1/A2[k][h] = Wlin-att dots; bnbe = bn + be --------
__global__ __launch_bounds__(256) void attw_k(
    const float* __restrict__ Wlin, const float* __restrict__ att,
    const float* __restrict__ bn, const float* __restrict__ be,
    float* __restrict__ A1, float* __restrict__ A2, float* __restrict__ bnbe)
{
    const int t = threadIdx.x;
    const int k = t & 127;
    const int pair = t >> 7;
    const float* wrow = Wlin + (size_t)k * 512;
    float s[4];
    #pragma unroll
    for (int h = 0; h < 4; h++) {
        float acc = 0.f;
        const float* ap = att + h * 256 + pair * 128;
        const float* wp = wrow + h * 128;
        for (int f = 0; f < 128; f++) acc += wp[f] * ap[f];
        s[h] = acc;
    }
    float* dst = (pair ? A2 : A1) + k * 4;
    dst[0] = s[0]; dst[1] = s[1]; dst[2] = s[2]; dst[3] = s[3];
    if (t < 128) bnbe[t] = bn[t] + be[t];
}

// -------- ax[r,h] = X[r,:] @ A1[:,h]  (one wave per row) --------
__global__ __launch_bounds__(256) void ax_k(
    const float* __restrict__ X, const float* __restrict__ A1,
    float* __restrict__ ax, int M)
{
    const int r = blockIdx.x * 4 + (threadIdx.x >> 6);
    const int lane = threadIdx.x & 63;
    if (r >= M) return;
    const int f0 = lane * 2;
    const float2 x = *(const float2*)(X + (size_t)r * 128 + f0);
    const float4 a0 = *(const float4*)(A1 + f0 * 4);
    const float4 a1 = *(const float4*)(A1 + f0 * 4 + 4);
    float s0 = x.x * a0.x + x.y * a1.x;
    float s1 = x.x * a0.y + x.y * a1.y;
    float s2 = x.x * a0.z + x.y * a1.z;
    float s3 = x.x * a0.w + x.y * a1.w;
    #pragma unroll
    for (int off = 1; off < 64; off <<= 1) {
        s0 += __shfl_xor(s0, off); s1 += __shfl_xor(s1, off);
        s2 += __shfl_xor(s2, off); s3 += __shfl_xor(s3, off);
    }
    if (lane == 0) *(float4*)(ax + (size_t)r * 4) = make_float4(s0, s1, s2, s3);
}

// -------- agg[e] = (1/deg) sum_j w * X[row[k]]  (bf16 out, E-path) --------
__global__ __launch_bounds__(256) void agg_k(
    const int* __restrict__ row, const float* __restrict__ adjv,
    const float* __restrict__ X, unsigned short* __restrict__ agg)
{
    const int e = blockIdx.x * 4 + (threadIdx.x >> 6);
    const int lane = threadIdx.x & 63;
    if (e >= ENUM) return;
    const int f0 = lane * 2;
    float a0 = 0.f, a1 = 0.f, deg = 0.f;
    #pragma unroll
    for (int j = 0; j < 8; j++) {
        const int k = e + j * ENUM;
        const float w = adjv[k];
        deg += w;
        const float2 x = *(const float2*)(X + (size_t)row[k] * 128 + f0);
        a0 += w * x.x; a1 += w * x.y;
    }
    const float rs = 1.f / deg;
    ((unsigned*)agg)[(size_t)e * 64 + lane] = pack2(a0 * rs, a1 * rs);
}

// ---- combined E GEMM: Eres = agg@Wn + E@We + bnbe + E  (f32 out) ----
__global__ __launch_bounds__(256) void gemme_k(
    const unsigned short* __restrict__ agg, const float* __restrict__ E,
    const unsigned short* __restrict__ WnT, const unsigned short* __restrict__ WeT,
    const float* __restrict__ bnbe, float* __restrict__ Eres, int M)
{
    __shared__ unsigned short Ag[64 * 128];
    __shared__ unsigned short Ae[64 * 128];
    __shared__ unsigned short Bw[64 * 128];
    __shared__ unsigned short Bv[64 * 128];
    const int tid = threadIdx.x;
    const int r0 = blockIdx.x * 64;

    {
        int rr = tid >> 4;
        const int kc = (tid & 15) * 8;
        #pragma unroll
        for (int it = 0; it < 4; it++) {
            int r = r0 + rr; if (r > M - 1) r = M - 1;
            const uint4 vg = *(const uint4*)(agg + (size_t)r * 128 + kc);
            const float* ep = E + (size_t)r * 128 + kc;
            const float4 f0 = *(const float4*)ep;
            const float4 f1 = *(const float4*)(ep + 4);
            uint4 ve;
            ve.x = pack2(f0.x, f0.y); ve.y = pack2(f0.z, f0.w);
            ve.z = pack2(f1.x, f1.y); ve.w = pack2(f1.z, f1.w);
            const int idx = (rr * 128 + kc) ^ ((rr & 7) << 3);
            *(uint4*)&Ag[idx] = vg;
            *(uint4*)&Ae[idx] = ve;
            rr += 16;
        }
    }
    __syncthreads();

    const int lane = tid & 63;
    const int wid = tid >> 6;
    const int wr = wid >> 1, wc = wid & 1;
    const int fr = lane & 15;
    const int kg = (lane >> 4) * 8;

    bf16x8 ag[2][4], ae_[2][4];
    #pragma unroll
    for (int m = 0; m < 2; m++) {
        const int ar = wr * 32 + m * 16 + fr;
        #pragma unroll
        for (int ks = 0; ks < 4; ks++) {
            const int idx = (ar * 128 + ks * 32 + kg) ^ ((ar & 7) << 3);
            ag[m][ks] = *(const bf16x8*)&Ag[idx];
            ae_[m][ks] = *(const bf16x8*)&Ae[idx];
        }
    }

    for (int ct = 0; ct < 2; ct++) {
        __syncthreads();
        {
            const unsigned short* s1 = WnT + (size_t)ct * 8192 + tid * 8;
            const unsigned short* s2 = WeT + (size_t)ct * 8192 + tid * 8;
            unsigned short* d1 = &Bw[tid * 8];
            unsigned short* d2 = &Bv[tid * 8];
            #pragma unroll
            for (int it = 0; it < 4; it++) {
                gload_lds16(s1 + it * 2048, d1 + it * 2048);
                gload_lds16(s2 + it * 2048, d2 + it * 2048);
            }
        }
        __syncthreads();

        f32x4 acc[2][2] = {};
        #pragma unroll
        for (int ks = 0; ks < 4; ks++) {
            bf16x8 bw[2], bv[2];
            #pragma unroll
            for (int n = 0; n < 2; n++) {
                const int br = wc * 32 + n * 16 + fr;
                const int idx = (br * 128 + ks * 32 + kg) ^ ((br & 7) << 3);
                bw[n] = *(const bf16x8*)&Bw[idx];
                bv[n] = *(const bf16x8*)&Bv[idx];
            }
            #pragma unroll
            for (int m = 0; m < 2; m++)
                #pragma unroll
                for (int n = 0; n < 2; n++) {
                    acc[m][n] = __builtin_amdgcn_mfma_f32_16x16x32_bf16(ag[m][ks], bw[n], acc[m][n], 0, 0, 0);
                    acc[m][n] = __builtin_amdgcn_mfma_f32_16x16x32_bf16(ae_[m][ks], bv[n], acc[m][n], 0, 0, 0);
                }
        }

        #pragma unroll
        for (int m = 0; m < 2; m++) {
            #pragma unroll
            for (int n = 0; n < 2; n++) {
                const int c = ct * 64 + wc * 32 + n * 16 + fr;
                #pragma unroll
                for (int j = 0; j < 4; j++) {
                    const int r = r0 + wr * 32 + m * 16 + (lane >> 4) * 4 + j;
                    if (r < M)
                        Eres[(size_t)r * 128 + c] = acc[m][n][j] + bnbe[c] + E[(size_t)r * 128 + c];
                }
            }
        }
    }
}

// -------- ae[e,h] = Eres[e,:] . A2[:,h] --------
__global__ __launch_bounds__(256) void ae_k(
    const float* __restrict__ Eres, const float* __restrict__ A2,
    float* __restrict__ ae)
{
    const int e = blockIdx.x * 4 + (threadIdx.x >> 6);
    const int lane = threadIdx.x & 63;
    if (e >= ENUM) return;
    const int f0 = lane * 2;
    const float2 v = *(const float2*)(Eres + (size_t)e * 128 + f0);
    const float4 a0 = *(const float4*)(A2 + f0 * 4);
    const float4 a1 = *(const float4*)(A2 + f0 * 4 + 4);
    float s0 = v.x * a0.x + v.y * a1.x;
    float s1 = v.x * a0.y + v.y * a1.y;
    float s2 = v.x * a0.z + v.y * a1.z;
    float s3 = v.x * a0.w + v.y * a1.w;
    #pragma unroll
    for (int off = 1; off < 64; off <<= 1) {
        s0 += __shfl_xor(s0, off); s1 += __shfl_xor(s1, off);
        s2 += __shfl_xor(s2, off); s3 += __shfl_xor(s3, off);
    }
    if (lane == 0) *(float4*)(ae + (size_t)e * 4) = make_float4(s0, s1, s2, s3);
}

// -------- CSR build --------
__global__ __launch_bounds__(256) void zero_k(unsigned* __restrict__ p, int n)
{
    const int t = blockIdx.x * 256 + threadIdx.x;
    if (t < n) p[t] = 0u;
}

__global__ __launch_bounds__(256) void hist_k(
    const int* __restrict__ row, int* __restrict__ cnt)
{
    const int k = blockIdx.x * 256 + threadIdx.x;
    if (k < NNZ_C) atomicAdd(cnt + row[k], 1);
}

__global__ __launch_bounds__(256) void scan1_k(
    const int* __restrict__ cnt, int* __restrict__ rp, int* __restrict__ bsum, int n)
{
    __shared__ int sh[256];
    const int t = threadIdx.x, g = blockIdx.x * 256 + t;
    const int v = (g < n) ? cnt[g] : 0;
    sh[t] = v; __syncthreads();
    #pragma unroll
    for (int off = 1; off < 256; off <<= 1) {
        const int add = (t >= off) ? sh[t - off] : 0;
        __syncthreads();
        sh[t] += add;
        __syncthreads();
    }
    if (g < n) rp[g] = sh[t] - v;
    if (t == 255) bsum[blockIdx.x] = sh[255];
}

__global__ __launch_bounds__(512) void scan2_k(int* __restrict__ bsum, int nb)
{
    __shared__ int sh[512];
    const int t = threadIdx.x;
    const int v = (t < nb) ? bsum[t] : 0;
    sh[t] = v; __syncthreads();
    #pragma unroll
    for (int off = 1; off < 512; off <<= 1) {
        const int add = (t >= off) ? sh[t - off] : 0;
        __syncthreads();
        sh[t] += add;
        __syncthreads();
    }
    if (t < nb) bsum[t] = sh[t] - v;
}

__global__ __launch_bounds__(256) void scan3_k(
    int* __restrict__ rp, const int* __restrict__ bsum, int* __restrict__ cur, int n)
{
    const int g = blockIdx.x * 256 + threadIdx.x;
    if (g < n) {
        const int v = rp[g] + bsum[g >> 8];
        rp[g] = v;
        cur[g] = v;
    }
    if (g == 0) rp[n] = NNZ_C;
}

__global__ __launch_bounds__(256) void fill_k(
    const int* __restrict__ row, int* __restrict__ cur, int* __restrict__ eidx)
{
    const int k = blockIdx.x * 256 + threadIdx.x;
    if (k < NNZ_C) {
        const int p = atomicAdd(cur + row[k], 1);
        eidx[p] = k;
    }
}

// -------- CSR softmax: one thread per row, 4 heads via float4 --------
__global__ __launch_bounds__(256) void softmax_csr_k(
    const int* __restrict__ rowptr, const int* __restrict__ eidx,
    const float* __restrict__ ax, const float* __restrict__ ae,
    float* __restrict__ alpha, float* __restrict__ alphag)
{
    const int r = blockIdx.x * 256 + threadIdx.x;
    if (r >= NN) return;
    const int p0 = rowptr[r], p1 = rowptr[r + 1];
    if (p0 == p1) return;
    const float4 axv = *(const float4*)(ax + (size_t)r * 4);

#define LRELU4(a) { a.x = (a.x >= 0.f) ? a.x : 0.2f * a.x;                    \
                    a.y = (a.y >= 0.f) ? a.y : 0.2f * a.y;                    \
                    a.z = (a.z >= 0.f) ? a.z : 0.2f * a.z;                    \
                    a.w = (a.w >= 0.f) ? a.w : 0.2f * a.w; }

    float4 m = make_float4(-1e30f, -1e30f, -1e30f, -1e30f);
    for (int p = p0; p < p1; ++p) {
        const int c = eidx[p] % ENUM;
        float4 a = *(const float4*)(ae + (size_t)c * 4);
        a.x += axv.x; a.y += axv.y; a.z += axv.z; a.w += axv.w;
        LRELU4(a);
        m.x = fmaxf(m.x, a.x); m.y = fmaxf(m.y, a.y);
        m.z = fmaxf(m.z, a.z); m.w = fmaxf(m.w, a.w);
    }
    float4 s = make_float4(0.f, 0.f, 0.f, 0.f);
    for (int p = p0; p < p1; ++p) {
        const int c = eidx[p] % ENUM;
        float4 a = *(const float4*)(ae + (size_t)c * 4);
        a.x += axv.x; a.y += axv.y; a.z += axv.z; a.w += axv.w;
        LRELU4(a);
        s.x += __expf(a.x - m.x); s.y += __expf(a.y - m.y);
        s.z += __expf(a.z - m.z); s.w += __expf(a.w - m.w);
    }
    const float4 rs = make_float4(1.f / s.x, 1.f / s.y, 1.f / s.z, 1.f / s.w);
    for (int p = p0; p < p1; ++p) {
        const int k = eidx[p];
        const int c = k % ENUM;
        float4 a = *(const float4*)(ae + (size_t)c * 4);
        a.x += axv.x; a.y += axv.y; a.z += axv.z; a.w += axv.w;
        LRELU4(a);
        float4 v;
        v.x = __expf(a.x - m.x) * rs.x; v.y = __expf(a.y - m.y) * rs.y;
        v.z = __expf(a.z - m.z) * rs.z; v.w = __expf(a.w - m.w) * rs.w;
        *(float4*)(alpha + ((size_t)k << 2)) = v;
        *(float4*)(alphag + ((size_t)p << 2)) = v;
    }
#undef LRELU4
}

// -------- aggX[e][(d,h)] = (1/8) sum_j alpha[k,h] * X[row[k],d]  (bf16) ----
__global__ __launch_bounds__(256) void aggx_k(
    const int* __restrict__ row, const float* __restrict__ alpha,
    const float* __restrict__ X, unsigned short* __restrict__ aggX)
{
    const int e = blockIdx.x * 4 + (threadIdx.x >> 6);
    const int lane = threadIdx.x & 63;
    if (e >= ENUM) return;
    const int f0 = lane * 2;
    float d0h0 = 0.f, d0h1 = 0.f, d0h2 = 0.f, d0h3 = 0.f;
    float d1h0 = 0.f, d1h1 = 0.f, d1h2 = 0.f, d1h3 = 0.f;
    #pragma unroll
    for (int j = 0; j < 8; j++) {
        const int k = e + j * ENUM;
        const float4 al = *(const float4*)(alpha + ((size_t)k << 2));
        const float2 x = *(const float2*)(X + (size_t)row[k] * 128 + f0);
        d0h0 += al.x * x.x; d0h1 += al.y * x.x; d0h2 += al.z * x.x; d0h3 += al.w * x.x;
        d1h0 += al.x * x.y; d1h1 += al.y * x.y; d1h2 += al.z * x.y; d1h3 += al.w * x.y;
    }
    uint4 o;
    o.x = pack2(0.125f * d0h0, 0.125f * d0h1);
    o.y = pack2(0.125f * d0h2, 0.125f * d0h3);
    o.z = pack2(0.125f * d1h0, 0.125f * d1h1);
    o.w = pack2(0.125f * d1h2, 0.125f * d1h3);
    *(uint4*)(aggX + (size_t)e * 512 + f0 * 4) = o;
}

// ---- FUSED node aggregation + final GEMM (K=512):
// A-tile rows computed on the fly: aggN[r][kk] = (0.25/Dn) sum_p al[p,h]*aggX[c][kk]
__global__ __launch_bounds__(256) void aggn_gemmf_k(
    const int* __restrict__ rowptr, const int* __restrict__ eidx,
    const float* __restrict__ adjv, const float* __restrict__ alphag,
    const unsigned short* __restrict__ aggX, const unsigned short* __restrict__ WbigT,
    const float* __restrict__ bias, float* __restrict__ Xres, int M)
{
    __shared__ unsigned short As[64 * 128];
    __shared__ unsigned short Bs[128 * 128];
    const int tid = threadIdx.x;
    const int r0 = blockIdx.x * 64;
    const int lane = tid & 63;
    const int w = tid >> 6;
    const int wr = w >> 1, wc = w & 1;   // wave: rows wr*32..+31, cols wc*64..+63
    const int fr = lane & 15;
    const int kg = (lane >> 4) * 8;

    // gather-role assignment: 4 threads per row, 32 kk each
    const int grow = tid >> 2;
    const int gq = tid & 3;
    int gp0 = 0, gp1 = 0;
    float gw = 0.f;
    {
        const int r = r0 + grow;
        if (r < M) {
            gp0 = rowptr[r];
            gp1 = rowptr[r + 1];
            float ds = 0.f;
            for (int p = gp0; p < gp1; ++p) ds += adjv[eidx[p] % ENUM];
            gw = (gp1 > gp0) ? 0.25f / ds : 0.f;
        }
    }

    f32x4 acc[2][4] = {};

    for (int kc = 0; kc < 4; kc++) {
        __syncthreads();   // prior As/Bs reads complete

        // ---- gather A chunk: row grow, kk in [kc*128 + gq*32, +32) ----
        {
            float v[32];
            #pragma unroll
            for (int i = 0; i < 32; i++) v[i] = 0.f;
            for (int p = gp0; p < gp1; ++p) {
                const int c = eidx[p] % ENUM;
                const float4 al = *(const float4*)(alphag + ((size_t)p << 2));
                const unsigned short* src = aggX + (size_t)c * 512 + kc * 128 + gq * 32;
                #pragma unroll
                for (int i = 0; i < 32; i += 8) {
                    const uint4 u = *(const uint4*)(src + i);
                    v[i + 0] += al.x * blo(u.x); v[i + 1] += al.y * bhi(u.x);
                    v[i + 2] += al.z * blo(u.y); v[i + 3] += al.w * bhi(u.y);
                    v[i + 4] += al.x * blo(u.z); v[i + 5] += al.y * bhi(u.z);
                    v[i + 6] += al.z * blo(u.w); v[i + 7] += al.w * bhi(u.w);
                }
            }
            #pragma unroll
            for (int i = 0; i < 32; i += 8) {
                uint4 o;
                o.x = pack2(gw * v[i + 0], gw * v[i + 1]);
                o.y = pack2(gw * v[i + 2], gw * v[i + 3]);
                o.z = pack2(gw * v[i + 4], gw * v[i + 5]);
                o.w = pack2(gw * v[i + 6], gw * v[i + 7]);
                *(uint4*)&As[(grow * 128 + gq * 32 + i) ^ ((grow & 7) << 3)] = o;
            }
        }
        // ---- stage B: chunk kc (32 KB, pre-swizzled, linear DMA) ----
        {
            const unsigned short* src = WbigT + (size_t)kc * 16384 + tid * 8;
            unsigned short* dst = &Bs[tid * 8];
            #pragma unroll
            for (int it = 0; it < 8; it++)
                gload_lds16(src + it * 2048, dst + it * 2048);
        }
        __syncthreads();

        #pragma unroll
        for (int ks = 0; ks < 4; ks++) {
            bf16x8 a[2], b[4];
            #pragma unroll
            for (int m = 0; m < 2; m++) {
                const int ar = wr * 32 + m * 16 + fr;
                a[m] = *(const bf16x8*)&As[(ar * 128 + ks * 32 + kg) ^ ((ar & 7) << 3)];
            }
            #pragma unroll
            for (int n = 0; n < 4; n++) {
                const int br = wc * 64 + n * 16 + fr;
                b[n] = *(const bf16x8*)&Bs[(br * 128 + ks * 32 + kg) ^ ((br & 7) << 3)];
            }
            #pragma unroll
            for (int m = 0; m < 2; m++)
                #pragma unroll
                for (int n = 0; n < 4; n++)
                    acc[m][n] = __builtin_amdgcn_mfma_f32_16x16x32_bf16(a[m], b[n], acc[m][n], 0, 0, 0);
        }
    }

    #pragma unroll
    for (int m = 0; m < 2; m++) {
        #pragma unroll
        for (int n = 0; n < 4; n++) {
            const int c = wc * 64 + n * 16 + fr;
            #pragma unroll
            for (int j = 0; j < 4; j++) {
                const int r = r0 + wr * 32 + m * 16 + (lane >> 4) * 4 + j;
                if (r < M)
                    Xres[(size_t)r * 128 + c] = acc[m][n][j] + bias[c];
            }
        }
    }
}

extern "C" void kernel_launch(void* const* d_in, const int* in_sizes, int n_in,
                              void* d_out, int out_size, void* d_ws, size_t ws_size,
                              hipStream_t stream)
{
    const float* X         = (const float*)d_in[0];
    const float* E         = (const float*)d_in[1];
    const int*   adj       = (const int*)d_in[2];
    const float* adjv      = (const float*)d_in[3];
    const float* Wn        = (const float*)d_in[4];
    const float* bn        = (const float*)d_in[5];
    const float* We        = (const float*)d_in[6];
    const float* be        = (const float*)d_in[7];
    const float* Wlin      = (const float*)d_in[8];
    const float* att       = (const float*)d_in[9];
    const float* bias_conv = (const float*)d_in[10];
    const int* row = adj;

    float* Xres = (float*)d_out;
    float* Eres = Xres + (size_t)NN * 128;

    // workspace layout (~62 MB)
    char* wsb = (char*)d_ws;
    unsigned short* aggX  = (unsigned short*)(wsb);              // 25.6 MB
    unsigned short* agg   = (unsigned short*)(wsb + 25600000);   // 6.5 MB
    unsigned short* WbigT = (unsigned short*)(wsb + 32200000);   // 128 KB (chunked+swz)
    unsigned short* WnT   = (unsigned short*)(wsb + 32331072);   // 32 KB (swz)
    unsigned short* WeT   = (unsigned short*)(wsb + 32363840);   // 32 KB (swz)
    float* A1    = (float*)(wsb + 32396608);                     // 2 KB
    float* A2    = (float*)(wsb + 32398656);                     // 2 KB
    float* bnbe  = (float*)(wsb + 32400704);                     // 512 B (rsv 2 KB)
    float* ax    = (float*)(wsb + 32402752);                     // 1.6 MB
    float* ae    = (float*)(wsb + 34002752);                     // 0.4 MB
    float* alpha = (float*)(wsb + 34402752);                     // 3.2 MB
    int* rowptr  = (int*)(wsb + 37602752);                       // 400,016 B
    int* cnt     = (int*)(wsb + 38002768);                       // 400,000 B
    int* eidx    = (int*)(wsb + 38402768);                       // 800,000 B
    int* bsum    = (int*)(wsb + 39202768);                       // 2 KB
    float* alphag= (float*)(wsb + 39204816);                     // 3.2 MB

    // ---- CSR build ----
    zero_k<<<(NN + 255) / 256, 256, 0, stream>>>((unsigned*)cnt, NN);
    hist_k<<<(NNZ_C + 255) / 256, 256, 0, stream>>>(row, cnt);
    scan1_k<<<(NN + 255) / 256, 256, 0, stream>>>(cnt, rowptr, bsum, NN);
    scan2_k<<<1, 512, 0, stream>>>(bsum, (NN + 255) / 256);
    scan3_k<<<(NN + 255) / 256, 256, 0, stream>>>(rowptr, bsum, cnt, NN);
    fill_k<<<(NNZ_C + 255) / 256, 256, 0, stream>>>(row, cnt, eidx);

    // ---- weight prep ----
    wtr_big_k<<<256, 256, 0, stream>>>(Wlin, WbigT);
    wtr_k<<<64, 256, 0, stream>>>(Wn, WnT, 128);
    wtr_k<<<64, 256, 0, stream>>>(We, WeT, 128);
    attw_k<<<1, 256, 0, stream>>>(Wlin, att, bn, be, A1, A2, bnbe);

    // ---- attention logits ----
    ax_k<<<NN / 4, 256, 0, stream>>>(X, A1, ax, NN);

    // ---- E path: agg -> combined GEMM -> ae ----
    agg_k<<<ENUM / 4, 256, 0, stream>>>(row, adjv, X, agg);
    gemme_k<<<391, 256, 0, stream>>>(agg, E, WnT, WeT, bnbe, Eres, ENUM);
    ae_k<<<ENUM / 4, 256, 0, stream>>>(Eres, A2, ae);

    // ---- CSR softmax ----
    softmax_csr_k<<<(NN + 255) / 256, 256, 0, stream>>>(rowptr, eidx, ax, ae, alpha, alphag);

    // ---- node -> hyperedge aggregation (pre-transform) ----
    aggx_k<<<ENUM / 4, 256, 0, stream>>>(row, alpha, X, aggX);

    // ---- FUSED hyperedge -> node aggregation + final K=512 GEMM ----
    aggn_gemmf_k<<<(NN + 63) / 64, 256, 0, stream>>>(
        rowptr, eidx, adjv, alphag, aggX, WbigT, bias_conv, Xres, NN);
}

// Round 18
// 215.041 us; speedup vs baseline: 1.1932x; 1.1932x over previous
//
#include <hip/hip_runtime.h>

#define NN 100000
#define ENUM 25000
#define NNZ_C 200000
// D = 128, H = 4, F = 128, Wlin: [128,512]
// Transform-after-first-aggregation:
//   aggX[e][h][d] = (1/8) sum_k alpha[k,h] X[row_k,d]        (bf16, [EN][4][128])
//   out_e[e][h][f] = aggX[e][h][:] @ Wlin_h                  (dense per-head GEMM)
//   Xres[r] = (0.25/Dn_r) sum_p sum_h alphag[p,h]*out_e[c_p][h][:] + bias
// E-path: agg = B^-1 A^T X ; Eres = agg@Wn + E@We + (bn+be) + E.
// Weights PRE-SWIZZLED in global (pos ^ ((row&7)<<3)) -> linear global_load_lds DMA.

typedef __attribute__((ext_vector_type(8))) short bf16x8;
typedef __attribute__((ext_vector_type(4))) float f32x4;

__device__ __forceinline__ float blo(unsigned u) { return __uint_as_float(u << 16); }
__device__ __forceinline__ float bhi(unsigned u) { return __uint_as_float(u & 0xFFFF0000u); }
__device__ __forceinline__ unsigned short f2bf(float x) {
    unsigned u = __float_as_uint(x);
    unsigned r = (u + 0x7fff + ((u >> 16) & 1)) >> 16;   // RNE
    return (unsigned short)r;
}
__device__ __forceinline__ unsigned pack2(float a, float b) {
    return (unsigned)f2bf(a) | ((unsigned)f2bf(b) << 16);
}
__device__ __forceinline__ void gload_lds16(const unsigned short* g, unsigned short* l) {
    __builtin_amdgcn_global_load_lds(
        (const __attribute__((address_space(1))) void*)g,
        (__attribute__((address_space(3))) void*)l, 16, 0, 0);
}

// -------- W[128][NC] f32 -> Wt bf16, row c, stored at swizzled position --------
__global__ __launch_bounds__(256) void wtr_k(
    const float* __restrict__ W, unsigned short* __restrict__ Wt, int NC)
{
    const int t = blockIdx.x * 256 + threadIdx.x;
    if (t >= 128 * NC) return;
    const int c = t % NC, k = t / NC;
    const size_t pos = ((size_t)c * 128 + k) ^ ((c & 7) << 3);
    Wt[pos] = f2bf(W[t]);
}

// -------- Wlin[128][512] -> WlinhT: 4 heads of [128 f][128 d], swizzled ----
// WlinhT[h][f][d] = Wlin[d][h*128+f]
__global__ __launch_bounds__(256) void wtr_h_k(
    const float* __restrict__ Wlin, unsigned short* __restrict__ WlinhT)
{
    const int t = blockIdx.x * 256 + threadIdx.x;
    if (t >= 128 * 512) return;
    const int d = t >> 9, c512 = t & 511;
    const int h = c512 >> 7, f = c512 & 127;
    const size_t pos = (size_t)h * 16384 + (((size_t)f * 128 + d) ^ ((f & 7) << 3));
    WlinhT[pos] = f2bf(Wlin[t]);
}

// -------- A1/A2[k][h] = Wlin-att dots; bnbe = bn + be --------
__global__ __launch_bounds__(256) void attw_k(
    const float* __restrict__ Wlin, const float* __restrict__ att,
    const float* __restrict__ bn, const float* __restrict__ be,
    float* __restrict__ A1, float* __restrict__ A2, float* __restrict__ bnbe)
{
    const int t = threadIdx.x;
    const int k = t & 127;
    const int pair = t >> 7;
    const float* wrow = Wlin + (size_t)k * 512;
    float s[4];
    #pragma unroll
    for (int h = 0; h < 4; h++) {
        float acc = 0.f;
        const float* ap = att + h * 256 + pair * 128;
        const float* wp = wrow + h * 128;
        for (int f = 0; f < 128; f++) acc += wp[f] * ap[f];
        s[h] = acc;
    }
    float* dst = (pair ? A2 : A1) + k * 4;
    dst[0] = s[0]; dst[1] = s[1]; dst[2] = s[2]; dst[3] = s[3];
    if (t < 128) bnbe[t] = bn[t] + be[t];
}

// -------- ax[r,h] = X[r,:] @ A1[:,h]  (one wave per row) --------
__global__ __launch_bounds__(256) void ax_k(
    const float* __restrict__ X, const float* __restrict__ A1,
    float* __restrict__ ax, int M)
{
    const int r = blockIdx.x * 4 + (threadIdx.x >> 6);
    const int lane = threadIdx.x & 63;
    if (r >= M) return;
    const int f0 = lane * 2;
    const float2 x = *(const float2*)(X + (size_t)r * 128 + f0);
    const float4 a0 = *(const float4*)(A1 + f0 * 4);
    const float4 a1 = *(const float4*)(A1 + f0 * 4 + 4);
    float s0 = x.x * a0.x + x.y * a1.x;
    float s1 = x.x * a0.y + x.y * a1.y;
    float s2 = x.x * a0.z + x.y * a1.z;
    float s3 = x.x * a0.w + x.y * a1.w;
    #pragma unroll
    for (int off = 1; off < 64; off <<= 1) {
        s0 += __shfl_xor(s0, off); s1 += __shfl_xor(s1, off);
        s2 += __shfl_xor(s2, off); s3 += __shfl_xor(s3, off);
    }
    if (lane == 0) *(float4*)(ax + (size_t)r * 4) = make_float4(s0, s1, s2, s3);
}

// -------- agg[e] = (1/deg) sum_j w * X[row[k]]  (bf16 out, E-path) --------
__global__ __launch_bounds__(256) void agg_k(
    const int* __restrict__ row, const float* __restrict__ adjv,
    const float* __restrict__ X, unsigned short* __restrict__ agg)
{
    const int e = blockIdx.x * 4 + (threadIdx.x >> 6);
    const int lane = threadIdx.x & 63;
    if (e >= ENUM) return;
    const int f0 = lane * 2;
    float a0 = 0.f, a1 = 0.f, deg = 0.f;
    #pragma unroll
    for (int j = 0; j < 8; j++) {
        const int k = e + j * ENUM;
        const float w = adjv[k];
        deg += w;
        const float2 x = *(const float2*)(X + (size_t)row[k] * 128 + f0);
        a0 += w * x.x; a1 += w * x.y;
    }
    const float rs = 1.f / deg;
    ((unsigned*)agg)[(size_t)e * 64 + lane] = pack2(a0 * rs, a1 * rs);
}

// ---- combined E GEMM: Eres = agg@Wn + E@We + bnbe + E  (f32 out) ----
__global__ __launch_bounds__(256) void gemme_k(
    const unsigned short* __restrict__ agg, const float* __restrict__ E,
    const unsigned short* __restrict__ WnT, const unsigned short* __restrict__ WeT,
    const float* __restrict__ bnbe, float* __restrict__ Eres, int M)
{
    __shared__ unsigned short Ag[64 * 128];
    __shared__ unsigned short Ae[64 * 128];
    __shared__ unsigned short Bw[64 * 128];
    __shared__ unsigned short Bv[64 * 128];
    const int tid = threadIdx.x;
    const int r0 = blockIdx.x * 64;

    {
        int rr = tid >> 4;
        const int kc = (tid & 15) * 8;
        #pragma unroll
        for (int it = 0; it < 4; it++) {
            int r = r0 + rr; if (r > M - 1) r = M - 1;
            const uint4 vg = *(const uint4*)(agg + (size_t)r * 128 + kc);
            const float* ep = E + (size_t)r * 128 + kc;
            const float4 f0 = *(const float4*)ep;
            const float4 f1 = *(const float4*)(ep + 4);
            uint4 ve;
            ve.x = pack2(f0.x, f0.y); ve.y = pack2(f0.z, f0.w);
            ve.z = pack2(f1.x, f1.y); ve.w = pack2(f1.z, f1.w);
            const int idx = (rr * 128 + kc) ^ ((rr & 7) << 3);
            *(uint4*)&Ag[idx] = vg;
            *(uint4*)&Ae[idx] = ve;
            rr += 16;
        }
    }
    __syncthreads();

    const int lane = tid & 63;
    const int wid = tid >> 6;
    const int wr = wid >> 1, wc = wid & 1;
    const int fr = lane & 15;
    const int kg = (lane >> 4) * 8;

    bf16x8 ag[2][4], ae_[2][4];
    #pragma unroll
    for (int m = 0; m < 2; m++) {
        const int ar = wr * 32 + m * 16 + fr;
        #pragma unroll
        for (int ks = 0; ks < 4; ks++) {
            const int idx = (ar * 128 + ks * 32 + kg) ^ ((ar & 7) << 3);
            ag[m][ks] = *(const bf16x8*)&Ag[idx];
            ae_[m][ks] = *(const bf16x8*)&Ae[idx];
        }
    }

    for (int ct = 0; ct < 2; ct++) {
        __syncthreads();
        {
            const unsigned short* s1 = WnT + (size_t)ct * 8192 + tid * 8;
            const unsigned short* s2 = WeT + (size_t)ct * 8192 + tid * 8;
            unsigned short* d1 = &Bw[tid * 8];
            unsigned short* d2 = &Bv[tid * 8];
            #pragma unroll
            for (int it = 0; it < 4; it++) {
                gload_lds16(s1 + it * 2048, d1 + it * 2048);
                gload_lds16(s2 + it * 2048, d2 + it * 2048);
            }
        }
        __syncthreads();

        f32x4 acc[2][2] = {};
        #pragma unroll
        for (int ks = 0; ks < 4; ks++) {
            bf16x8 bw[2], bv[2];
            #pragma unroll
            for (int n = 0; n < 2; n++) {
                const int br = wc * 32 + n * 16 + fr;
                const int idx = (br * 128 + ks * 32 + kg) ^ ((br & 7) << 3);
                bw[n] = *(const bf16x8*)&Bw[idx];
                bv[n] = *(const bf16x8*)&Bv[idx];
            }
            #pragma unroll
            for (int m = 0; m < 2; m++)
                #pragma unroll
                for (int n = 0; n < 2; n++) {
                    acc[m][n] = __builtin_amdgcn_mfma_f32_16x16x32_bf16(ag[m][ks], bw[n], acc[m][n], 0, 0, 0);
                    acc[m][n] = __builtin_amdgcn_mfma_f32_16x16x32_bf16(ae_[m][ks], bv[n], acc[m][n], 0, 0, 0);
                }
        }

        #pragma unroll
        for (int m = 0; m < 2; m++) {
            #pragma unroll
            for (int n = 0; n < 2; n++) {
                const int c = ct * 64 + wc * 32 + n * 16 + fr;
                #pragma unroll
                for (int j = 0; j < 4; j++) {
                    const int r = r0 + wr * 32 + m * 16 + (lane >> 4) * 4 + j;
                    if (r < M)
                        Eres[(size_t)r * 128 + c] = acc[m][n][j] + bnbe[c] + E[(size_t)r * 128 + c];
                }
            }
        }
    }
}

// -------- ae[e,h] = Eres[e,:] . A2[:,h] --------
__global__ __launch_bounds__(256) void ae_k(
    const float* __restrict__ Eres, const float* __restrict__ A2,
    float* __restrict__ ae)
{
    const int e = blockIdx.x * 4 + (threadIdx.x >> 6);
    const int lane = threadIdx.x & 63;
    if (e >= ENUM) return;
    const int f0 = lane * 2;
    const float2 v = *(const float2*)(Eres + (size_t)e * 128 + f0);
    const float4 a0 = *(const float4*)(A2 + f0 * 4);
    const float4 a1 = *(const float4*)(A2 + f0 * 4 + 4);
    float s0 = v.x * a0.x + v.y * a1.x;
    float s1 = v.x * a0.y + v.y * a1.y;
    float s2 = v.x * a0.z + v.y * a1.z;
    float s3 = v.x * a0.w + v.y * a1.w;
    #pragma unroll
    for (int off = 1; off < 64; off <<= 1) {
        s0 += __shfl_xor(s0, off); s1 += __shfl_xor(s1, off);
        s2 += __shfl_xor(s2, off); s3 += __shfl_xor(s3, off);
    }
    if (lane == 0) *(float4*)(ae + (size_t)e * 4) = make_float4(s0, s1, s2, s3);
}

// -------- CSR build --------
__global__ __launch_bounds__(256) void zero_k(unsigned* __restrict__ p, int n)
{
    const int t = blockIdx.x * 256 + threadIdx.x;
    if (t < n) p[t] = 0u;
}

__global__ __launch_bounds__(256) void hist_k(
    const int* __restrict__ row, int* __restrict__ cnt)
{
    const int k = blockIdx.x * 256 + threadIdx.x;
    if (k < NNZ_C) atomicAdd(cnt + row[k], 1);
}

__global__ __launch_bounds__(256) void scan1_k(
    const int* __restrict__ cnt, int* __restrict__ rp, int* __restrict__ bsum, int n)
{
    __shared__ int sh[256];
    const int t = threadIdx.x, g = blockIdx.x * 256 + t;
    const int v = (g < n) ? cnt[g] : 0;
    sh[t] = v; __syncthreads();
    #pragma unroll
    for (int off = 1; off < 256; off <<= 1) {
        const int add = (t >= off) ? sh[t - off] : 0;
        __syncthreads();
        sh[t] += add;
        __syncthreads();
    }
    if (g < n) rp[g] = sh[t] - v;
    if (t == 255) bsum[blockIdx.x] = sh[255];
}

__global__ __launch_bounds__(512) void scan2_k(int* __restrict__ bsum, int nb)
{
    __shared__ int sh[512];
    const int t = threadIdx.x;
    const int v = (t < nb) ? bsum[t] : 0;
    sh[t] = v; __syncthreads();
    #pragma unroll
    for (int off = 1; off < 512; off <<= 1) {
        const int add = (t >= off) ? sh[t - off] : 0;
        __syncthreads();
        sh[t] += add;
        __syncthreads();
    }
    if (t < nb) bsum[t] = sh[t] - v;
}

__global__ __launch_bounds__(256) void scan3_k(
    int* __restrict__ rp, const int* __restrict__ bsum, int* __restrict__ cur, int n)
{
    const int g = blockIdx.x * 256 + threadIdx.x;
    if (g < n) {
        const int v = rp[g] + bsum[g >> 8];
        rp[g] = v;
        cur[g] = v;
    }
    if (g == 0) rp[n] = NNZ_C;
}

__global__ __launch_bounds__(256) void fill_k(
    const int* __restrict__ row, int* __restrict__ cur, int* __restrict__ eidx)
{
    const int k = blockIdx.x * 256 + threadIdx.x;
    if (k < NNZ_C) {
        const int p = atomicAdd(cur + row[k], 1);
        eidx[p] = k;
    }
}

// -------- CSR softmax: one thread per row, 4 heads via float4 --------
__global__ __launch_bounds__(256) void softmax_csr_k(
    const int* __restrict__ rowptr, const int* __restrict__ eidx,
    const float* __restrict__ ax, const float* __restrict__ ae,
    float* __restrict__ alpha, float* __restrict__ alphag)
{
    const int r = blockIdx.x * 256 + threadIdx.x;
    if (r >= NN) return;
    const int p0 = rowptr[r], p1 = rowptr[r + 1];
    if (p0 == p1) return;
    const float4 axv = *(const float4*)(ax + (size_t)r * 4);

#define LRELU4(a) { a.x = (a.x >= 0.f) ? a.x : 0.2f * a.x;                    \
                    a.y = (a.y >= 0.f) ? a.y : 0.2f * a.y;                    \
                    a.z = (a.z >= 0.f) ? a.z : 0.2f * a.z;                    \
                    a.w = (a.w >= 0.f) ? a.w : 0.2f * a.w; }

    float4 m = make_float4(-1e30f, -1e30f, -1e30f, -1e30f);
    for (int p = p0; p < p1; ++p) {
        const int c = eidx[p] % ENUM;
        float4 a = *(const float4*)(ae + (size_t)c * 4);
        a.x += axv.x; a.y += axv.y; a.z += axv.z; a.w += axv.w;
        LRELU4(a);
        m.x = fmaxf(m.x, a.x); m.y = fmaxf(m.y, a.y);
        m.z = fmaxf(m.z, a.z); m.w = fmaxf(m.w, a.w);
    }
    float4 s = make_float4(0.f, 0.f, 0.f, 0.f);
    for (int p = p0; p < p1; ++p) {
        const int c = eidx[p] % ENUM;
        float4 a = *(const float4*)(ae + (size_t)c * 4);
        a.x += axv.x; a.y += axv.y; a.z += axv.z; a.w += axv.w;
        LRELU4(a);
        s.x += __expf(a.x - m.x); s.y += __expf(a.y - m.y);
        s.z += __expf(a.z - m.z); s.w += __expf(a.w - m.w);
    }
    const float4 rs = make_float4(1.f / s.x, 1.f / s.y, 1.f / s.z, 1.f / s.w);
    for (int p = p0; p < p1; ++p) {
        const int k = eidx[p];
        const int c = k % ENUM;
        float4 a = *(const float4*)(ae + (size_t)c * 4);
        a.x += axv.x; a.y += axv.y; a.z += axv.z; a.w += axv.w;
        LRELU4(a);
        float4 v;
        v.x = __expf(a.x - m.x) * rs.x; v.y = __expf(a.y - m.y) * rs.y;
        v.z = __expf(a.z - m.z) * rs.z; v.w = __expf(a.w - m.w) * rs.w;
        *(float4*)(alpha + ((size_t)k << 2)) = v;
        *(float4*)(alphag + ((size_t)p << 2)) = v;
    }
#undef LRELU4
}

// -------- aggX[e][h][d] = (1/8) sum_j alpha[k,h] * X[row[k],d]  (bf16) ----
__global__ __launch_bounds__(256) void aggx_k(
    const int* __restrict__ row, const float* __restrict__ alpha,
    const float* __restrict__ X, unsigned short* __restrict__ aggX)
{
    const int e = blockIdx.x * 4 + (threadIdx.x >> 6);
    const int lane = threadIdx.x & 63;
    if (e >= ENUM) return;
    const int d0 = lane * 2;
    float h0a = 0.f, h0b = 0.f, h1a = 0.f, h1b = 0.f;
    float h2a = 0.f, h2b = 0.f, h3a = 0.f, h3b = 0.f;
    #pragma unroll
    for (int j = 0; j < 8; j++) {
        const int k = e + j * ENUM;
        const float4 al = *(const float4*)(alpha + ((size_t)k << 2));
        const float2 x = *(const float2*)(X + (size_t)row[k] * 128 + d0);
        h0a += al.x * x.x; h0b += al.x * x.y;
        h1a += al.y * x.x; h1b += al.y * x.y;
        h2a += al.z * x.x; h2b += al.z * x.y;
        h3a += al.w * x.x; h3b += al.w * x.y;
    }
    unsigned* dst = (unsigned*)aggX + (size_t)e * 256 + lane;
    dst[0]   = pack2(0.125f * h0a, 0.125f * h0b);
    dst[64]  = pack2(0.125f * h1a, 0.125f * h1b);
    dst[128] = pack2(0.125f * h2a, 0.125f * h2b);
    dst[192] = pack2(0.125f * h3a, 0.125f * h3b);
}

// -------- out_e[e][h][f] = aggX[e][h][:] @ Wlin_h  (per-head K=128 MFMA GEMM) ----
__global__ __launch_bounds__(256) void gemmoe_k(
    const unsigned short* __restrict__ aggX, const unsigned short* __restrict__ WlinhT,
    unsigned short* __restrict__ out_e, int M)
{
    __shared__ unsigned short As[64 * 128];
    __shared__ unsigned short Bs[128 * 128];
    const int tid = threadIdx.x;
    const int r0 = blockIdx.x * 64;
    const int lane = tid & 63;
    const int w = tid >> 6;
    const int wr = w >> 1, wc = w & 1;   // wave: rows wr*32..+31, cols wc*64..+63
    const int fr = lane & 15;
    const int kg = (lane >> 4) * 8;

    for (int h = 0; h < 4; h++) {
        __syncthreads();   // prior As/Bs reads complete
        // stage A: 64 edges x 128 d of head h (reg + swizzle)
        {
            int rr = tid >> 4;
            const int kc = (tid & 15) * 8;
            #pragma unroll
            for (int it = 0; it < 4; it++) {
                int r = r0 + rr; if (r > M - 1) r = M - 1;
                const uint4 va = *(const uint4*)(aggX + (size_t)r * 512 + h * 128 + kc);
                *(uint4*)&As[(rr * 128 + kc) ^ ((rr & 7) << 3)] = va;
                rr += 16;
            }
        }
        // stage B: head h (32 KB, pre-swizzled, linear DMA)
        {
            const unsigned short* src = WlinhT + (size_t)h * 16384 + tid * 8;
            unsigned short* dst = &Bs[tid * 8];
            #pragma unroll
            for (int it = 0; it < 8; it++)
                gload_lds16(src + it * 2048, dst + it * 2048);
        }
        __syncthreads();

        f32x4 acc[2][4] = {};
        #pragma unroll
        for (int ks = 0; ks < 4; ks++) {
            bf16x8 a[2], b[4];
            #pragma unroll
            for (int m = 0; m < 2; m++) {
                const int ar = wr * 32 + m * 16 + fr;
                a[m] = *(const bf16x8*)&As[(ar * 128 + ks * 32 + kg) ^ ((ar & 7) << 3)];
            }
            #pragma unroll
            for (int n = 0; n < 4; n++) {
                const int br = wc * 64 + n * 16 + fr;
                b[n] = *(const bf16x8*)&Bs[(br * 128 + ks * 32 + kg) ^ ((br & 7) << 3)];
            }
            #pragma unroll
            for (int m = 0; m < 2; m++)
                #pragma unroll
                for (int n = 0; n < 4; n++)
                    acc[m][n] = __builtin_amdgcn_mfma_f32_16x16x32_bf16(a[m], b[n], acc[m][n], 0, 0, 0);
        }

        #pragma unroll
        for (int m = 0; m < 2; m++) {
            #pragma unroll
            for (int n = 0; n < 4; n++) {
                const int c = wc * 64 + n * 16 + fr;
                #pragma unroll
                for (int j = 0; j < 4; j++) {
                    const int r = r0 + wr * 32 + m * 16 + (lane >> 4) * 4 + j;
                    if (r < M)
                        out_e[(size_t)r * 512 + h * 128 + c] = f2bf(acc[m][n][j]);
                }
            }
        }
    }
}

// -------- final CSR gather: out_e [e][h][f] layout, alphag sequential --------
__global__ __launch_bounds__(256) void xgather_k(
    const int* __restrict__ rowptr, const int* __restrict__ eidx,
    const float* __restrict__ adjv, const float* __restrict__ alphag,
    const unsigned short* __restrict__ out_e, const float* __restrict__ bias,
    float* __restrict__ Xres)
{
    const int r = blockIdx.x * 4 + (threadIdx.x >> 6);
    const int lane = threadIdx.x & 63;
    if (r >= NN) return;
    const int p0 = rowptr[r], p1 = rowptr[r + 1];
    const int f0 = lane * 2;
    float a0 = 0.f, a1 = 0.f, ds = 0.f;

#define XG_BODY(P) {                                                          \
        const int c = eidx[P] % ENUM;                                         \
        ds += adjv[c];                                                        \
        const float4 al = *(const float4*)(alphag + ((size_t)(P) << 2));      \
        const unsigned* ob = (const unsigned*)out_e + (size_t)c * 256 + lane; \
        const unsigned u0 = ob[0], u1 = ob[64], u2 = ob[128], u3 = ob[192];   \
        a0 += al.x * blo(u0) + al.y * blo(u1) + al.z * blo(u2) + al.w * blo(u3); \
        a1 += al.x * bhi(u0) + al.y * bhi(u1) + al.z * bhi(u2) + al.w * bhi(u3); \
    }

    int p = p0;
    for (; p + 2 <= p1; p += 2) { XG_BODY(p); XG_BODY(p + 1); }
    if (p < p1) XG_BODY(p);
#undef XG_BODY

    const float w = (p1 > p0) ? 0.25f / ds : 0.f;
    float2 o;
    o.x = bias[f0] + w * a0;
    o.y = bias[f0 + 1] + w * a1;
    *(float2*)(Xres + (size_t)r * 128 + f0) = o;
}

extern "C" void kernel_launch(void* const* d_in, const int* in_sizes, int n_in,
                              void* d_out, int out_size, void* d_ws, size_t ws_size,
                              hipStream_t stream)
{
    const float* X         = (const float*)d_in[0];
    const float* E         = (const float*)d_in[1];
    const int*   adj       = (const int*)d_in[2];
    const float* adjv      = (const float*)d_in[3];
    const float* Wn        = (const float*)d_in[4];
    const float* bn        = (const float*)d_in[5];
    const float* We        = (const float*)d_in[6];
    const float* be        = (const float*)d_in[7];
    const float* Wlin      = (const float*)d_in[8];
    const float* att       = (const float*)d_in[9];
    const float* bias_conv = (const float*)d_in[10];
    const int* row = adj;

    float* Xres = (float*)d_out;
    float* Eres = Xres + (size_t)NN * 128;

    // workspace layout (~68 MB)
    char* wsb = (char*)d_ws;
    unsigned short* aggX  = (unsigned short*)(wsb);              // 25.6 MB
    unsigned short* out_e = (unsigned short*)(wsb + 25600000);   // 25.6 MB
    unsigned short* agg   = (unsigned short*)(wsb + 51200000);   // 6.5 MB
    unsigned short* WlinhT= (unsigned short*)(wsb + 57800000);   // 128 KB (per-head, swz)
    unsigned short* WnT   = (unsigned short*)(wsb + 57931072);   // 32 KB (swz)
    unsigned short* WeT   = (unsigned short*)(wsb + 57963840);   // 32 KB (swz)
    float* A1    = (float*)(wsb + 57996608);                     // 2 KB
    float* A2    = (float*)(wsb + 57998656);                     // 2 KB
    float* bnbe  = (float*)(wsb + 58000704);                     // 512 B (rsv 2 KB)
    float* ax    = (float*)(wsb + 58002752);                     // 1.6 MB
    float* ae    = (float*)(wsb + 59602752);                     // 0.4 MB
    float* alpha = (float*)(wsb + 60002752);                     // 3.2 MB
    int* rowptr  = (int*)(wsb + 63202752);                       // 400,016 B
    int* cnt     = (int*)(wsb + 63602768);                       // 400,000 B
    int* eidx    = (int*)(wsb + 64002768);                       // 800,000 B
    int* bsum    = (int*)(wsb + 64802768);                       // 2 KB
    float* alphag= (float*)(wsb + 64804816);                     // 3.2 MB

    // ---- CSR build ----
    zero_k<<<(NN + 255) / 256, 256, 0, stream>>>((unsigned*)cnt, NN);
    hist_k<<<(NNZ_C + 255) / 256, 256, 0, stream>>>(row, cnt);
    scan1_k<<<(NN + 255) / 256, 256, 0, stream>>>(cnt, rowptr, bsum, NN);
    scan2_k<<<1, 512, 0, stream>>>(bsum, (NN + 255) / 256);
    scan3_k<<<(NN + 255) / 256, 256, 0, stream>>>(rowptr, bsum, cnt, NN);
    fill_k<<<(NNZ_C + 255) / 256, 256, 0, stream>>>(row, cnt, eidx);

    // ---- weight prep ----
    wtr_h_k<<<256, 256, 0, stream>>>(Wlin, WlinhT);
    wtr_k<<<64, 256, 0, stream>>>(Wn, WnT, 128);
    wtr_k<<<64, 256, 0, stream>>>(We, WeT, 128);
    attw_k<<<1, 256, 0, stream>>>(Wlin, att, bn, be, A1, A2, bnbe);

    // ---- attention logits ----
    ax_k<<<NN / 4, 256, 0, stream>>>(X, A1, ax, NN);

    // ---- E path: agg -> combined GEMM -> ae ----
    agg_k<<<ENUM / 4, 256, 0, stream>>>(row, adjv, X, agg);
    gemme_k<<<391, 256, 0, stream>>>(agg, E, WnT, WeT, bnbe, Eres, ENUM);
    ae_k<<<ENUM / 4, 256, 0, stream>>>(Eres, A2, ae);

    // ---- CSR softmax ----
    softmax_csr_k<<<(NN + 255) / 256, 256, 0, stream>>>(rowptr, eidx, ax, ae, alpha, alphag);

    // ---- node -> hyperedge aggregation (pre-transform) ----
    aggx_k<<<ENUM / 4, 256, 0, stream>>>(row, alpha, X, aggX);

    // ---- per-head transform: out_e = aggX @ Wlin_h ----
    gemmoe_k<<<(ENUM + 63) / 64, 256, 0, stream>>>(aggX, WlinhT, out_e, ENUM);

    // ---- hyperedge -> node: CSR gather ----
    xgather_k<<<NN / 4, 256, 0, stream>>>(rowptr, eidx, adjv, alphag, out_e, bias_conv, Xres);
}

// Round 19
// 205.392 us; speedup vs baseline: 1.2492x; 1.0470x over previous
//
#include <hip/hip_runtime.h>

#define NN 100000
#define ENUM 25000
#define NNZ_C 200000
// D = 128, H = 4, F = 128, Wlin: [128,512]
// Transform-after-first-aggregation:
//   aggX[e][h][d] = (1/8) sum_k alpha[k,h] X[row_k,d]        (bf16, [EN][4][128])
//   out_e[e][h][f] = aggX[e][h][:] @ Wlin_h                  (dense per-head GEMM)
//   Xres[r] = sum_p sum_h alphag[p,h]*out_e[c_p][h][:] + bias   (alphag pre-scaled by 0.25/Dn)
// E-path: agg = B^-1 A^T X ; Eres = agg@Wn + E@We + (bn+be) + E.
// Weights PRE-SWIZZLED in global (pos ^ ((row&7)<<3)) -> linear global_load_lds DMA.

typedef __attribute__((ext_vector_type(8))) short bf16x8;
typedef __attribute__((ext_vector_type(4))) float f32x4;

__device__ __forceinline__ float blo(unsigned u) { return __uint_as_float(u << 16); }
__device__ __forceinline__ float bhi(unsigned u) { return __uint_as_float(u & 0xFFFF0000u); }
__device__ __forceinline__ unsigned short f2bf(float x) {
    unsigned u = __float_as_uint(x);
    unsigned r = (u + 0x7fff + ((u >> 16) & 1)) >> 16;   // RNE
    return (unsigned short)r;
}
__device__ __forceinline__ unsigned pack2(float a, float b) {
    return (unsigned)f2bf(a) | ((unsigned)f2bf(b) << 16);
}
__device__ __forceinline__ void gload_lds16(const unsigned short* g, unsigned short* l) {
    __builtin_amdgcn_global_load_lds(
        (const __attribute__((address_space(1))) void*)g,
        (__attribute__((address_space(3))) void*)l, 16, 0, 0);
}

// ---- fused prep: WlinhT (256 blks) | WnT (64) | WeT (64) | attw+bnbe (1) | zero cnt (391) ----
__global__ __launch_bounds__(256) void prep_k(
    const float* __restrict__ Wlin, const float* __restrict__ Wn,
    const float* __restrict__ We, const float* __restrict__ att,
    const float* __restrict__ bn, const float* __restrict__ be,
    unsigned short* __restrict__ WlinhT, unsigned short* __restrict__ WnT,
    unsigned short* __restrict__ WeT, float* __restrict__ A1,
    float* __restrict__ A2, float* __restrict__ bnbe, int* __restrict__ cnt)
{
    const int bid = blockIdx.x;
    if (bid < 256) {
        // WlinhT[h][f][d] = Wlin[d][h*128+f], swizzled
        const int t = bid * 256 + threadIdx.x;
        const int d = t >> 9, c512 = t & 511;
        const int h = c512 >> 7, f = c512 & 127;
        const size_t pos = (size_t)h * 16384 + (((size_t)f * 128 + d) ^ ((f & 7) << 3));
        WlinhT[pos] = f2bf(Wlin[t]);
    } else if (bid < 320) {
        const int t = (bid - 256) * 256 + threadIdx.x;
        const int c = t & 127, k = t >> 7;
        WnT[(((size_t)c * 128 + k) ^ ((c & 7) << 3))] = f2bf(Wn[t]);
    } else if (bid < 384) {
        const int t = (bid - 320) * 256 + threadIdx.x;
        const int c = t & 127, k = t >> 7;
        WeT[(((size_t)c * 128 + k) ^ ((c & 7) << 3))] = f2bf(We[t]);
    } else if (bid == 384) {
        const int t = threadIdx.x;
        const int k = t & 127;
        const int pair = t >> 7;
        const float* wrow = Wlin + (size_t)k * 512;
        float s[4];
        #pragma unroll
        for (int h = 0; h < 4; h++) {
            float acc = 0.f;
            const float* ap = att + h * 256 + pair * 128;
            const float* wp = wrow + h * 128;
            for (int f = 0; f < 128; f++) acc += wp[f] * ap[f];
            s[h] = acc;
        }
        float* dst = (pair ? A2 : A1) + k * 4;
        dst[0] = s[0]; dst[1] = s[1]; dst[2] = s[2]; dst[3] = s[3];
        if (t < 128) bnbe[t] = bn[t] + be[t];
    } else {
        const int t = (bid - 385) * 256 + threadIdx.x;
        if (t < NN) cnt[t] = 0;
    }
}

// -------- ax[r,h] = X[r,:] @ A1[:,h]  (one wave per row) --------
__global__ __launch_bounds__(256) void ax_k(
    const float* __restrict__ X, const float* __restrict__ A1,
    float* __restrict__ ax, int M)
{
    const int r = blockIdx.x * 4 + (threadIdx.x >> 6);
    const int lane = threadIdx.x & 63;
    if (r >= M) return;
    const int f0 = lane * 2;
    const float2 x = *(const float2*)(X + (size_t)r * 128 + f0);
    const float4 a0 = *(const float4*)(A1 + f0 * 4);
    const float4 a1 = *(const float4*)(A1 + f0 * 4 + 4);
    float s0 = x.x * a0.x + x.y * a1.x;
    float s1 = x.x * a0.y + x.y * a1.y;
    float s2 = x.x * a0.z + x.y * a1.z;
    float s3 = x.x * a0.w + x.y * a1.w;
    #pragma unroll
    for (int off = 1; off < 64; off <<= 1) {
        s0 += __shfl_xor(s0, off); s1 += __shfl_xor(s1, off);
        s2 += __shfl_xor(s2, off); s3 += __shfl_xor(s3, off);
    }
    if (lane == 0) *(float4*)(ax + (size_t)r * 4) = make_float4(s0, s1, s2, s3);
}

// -------- agg[e] = (1/deg) sum_j w * X[row[k]]  (bf16 out, E-path) --------
__global__ __launch_bounds__(256) void agg_k(
    const int* __restrict__ row, const float* __restrict__ adjv,
    const float* __restrict__ X, unsigned short* __restrict__ agg)
{
    const int e = blockIdx.x * 4 + (threadIdx.x >> 6);
    const int lane = threadIdx.x & 63;
    if (e >= ENUM) return;
    const int f0 = lane * 2;
    float a0 = 0.f, a1 = 0.f, deg = 0.f;
    #pragma unroll
    for (int j = 0; j < 8; j++) {
        const int k = e + j * ENUM;
        const float w = adjv[k];
        deg += w;
        const float2 x = *(const float2*)(X + (size_t)row[k] * 128 + f0);
        a0 += w * x.x; a1 += w * x.y;
    }
    const float rs = 1.f / deg;
    ((unsigned*)agg)[(size_t)e * 64 + lane] = pack2(a0 * rs, a1 * rs);
}

// ---- combined E GEMM: Eres = agg@Wn + E@We + bnbe + E  (f32 out) ----
__global__ __launch_bounds__(256) void gemme_k(
    const unsigned short* __restrict__ agg, const float* __restrict__ E,
    const unsigned short* __restrict__ WnT, const unsigned short* __restrict__ WeT,
    const float* __restrict__ bnbe, float* __restrict__ Eres, int M)
{
    __shared__ unsigned short Ag[64 * 128];
    __shared__ unsigned short Ae[64 * 128];
    __shared__ unsigned short Bw[64 * 128];
    __shared__ unsigned short Bv[64 * 128];
    const int tid = threadIdx.x;
    const int r0 = blockIdx.x * 64;

    {
        int rr = tid >> 4;
        const int kc = (tid & 15) * 8;
        #pragma unroll
        for (int it = 0; it < 4; it++) {
            int r = r0 + rr; if (r > M - 1) r = M - 1;
            const uint4 vg = *(const uint4*)(agg + (size_t)r * 128 + kc);
            const float* ep = E + (size_t)r * 128 + kc;
            const float4 f0 = *(const float4*)ep;
            const float4 f1 = *(const float4*)(ep + 4);
            uint4 ve;
            ve.x = pack2(f0.x, f0.y); ve.y = pack2(f0.z, f0.w);
            ve.z = pack2(f1.x, f1.y); ve.w = pack2(f1.z, f1.w);
            const int idx = (rr * 128 + kc) ^ ((rr & 7) << 3);
            *(uint4*)&Ag[idx] = vg;
            *(uint4*)&Ae[idx] = ve;
            rr += 16;
        }
    }
    __syncthreads();

    const int lane = tid & 63;
    const int wid = tid >> 6;
    const int wr = wid >> 1, wc = wid & 1;
    const int fr = lane & 15;
    const int kg = (lane >> 4) * 8;

    bf16x8 ag[2][4], ae_[2][4];
    #pragma unroll
    for (int m = 0; m < 2; m++) {
        const int ar = wr * 32 + m * 16 + fr;
        #pragma unroll
        for (int ks = 0; ks < 4; ks++) {
            const int idx = (ar * 128 + ks * 32 + kg) ^ ((ar & 7) << 3);
            ag[m][ks] = *(const bf16x8*)&Ag[idx];
            ae_[m][ks] = *(const bf16x8*)&Ae[idx];
        }
    }

    for (int ct = 0; ct < 2; ct++) {
        __syncthreads();
        {
            const unsigned short* s1 = WnT + (size_t)ct * 8192 + tid * 8;
            const unsigned short* s2 = WeT + (size_t)ct * 8192 + tid * 8;
            unsigned short* d1 = &Bw[tid * 8];
            unsigned short* d2 = &Bv[tid * 8];
            #pragma unroll
            for (int it = 0; it < 4; it++) {
                gload_lds16(s1 + it * 2048, d1 + it * 2048);
                gload_lds16(s2 + it * 2048, d2 + it * 2048);
            }
        }
        __syncthreads();

        f32x4 acc[2][2] = {};
        #pragma unroll
        for (int ks = 0; ks < 4; ks++) {
            bf16x8 bw[2], bv[2];
            #pragma unroll
            for (int n = 0; n < 2; n++) {
                const int br = wc * 32 + n * 16 + fr;
                const int idx = (br * 128 + ks * 32 + kg) ^ ((br & 7) << 3);
                bw[n] = *(const bf16x8*)&Bw[idx];
                bv[n] = *(const bf16x8*)&Bv[idx];
            }
            #pragma unroll
            for (int m = 0; m < 2; m++)
                #pragma unroll
                for (int n = 0; n < 2; n++) {
                    acc[m][n] = __builtin_amdgcn_mfma_f32_16x16x32_bf16(ag[m][ks], bw[n], acc[m][n], 0, 0, 0);
                    acc[m][n] = __builtin_amdgcn_mfma_f32_16x16x32_bf16(ae_[m][ks], bv[n], acc[m][n], 0, 0, 0);
                }
        }

        #pragma unroll
        for (int m = 0; m < 2; m++) {
            #pragma unroll
            for (int n = 0; n < 2; n++) {
                const int c = ct * 64 + wc * 32 + n * 16 + fr;
                #pragma unroll
                for (int j = 0; j < 4; j++) {
                    const int r = r0 + wr * 32 + m * 16 + (lane >> 4) * 4 + j;
                    if (r < M)
                        Eres[(size_t)r * 128 + c] = acc[m][n][j] + bnbe[c] + E[(size_t)r * 128 + c];
                }
            }
        }
    }
}

// -------- ae[e,h] = Eres[e,:] . A2[:,h] --------
__global__ __launch_bounds__(256) void ae_k(
    const float* __restrict__ Eres, const float* __restrict__ A2,
    float* __restrict__ ae)
{
    const int e = blockIdx.x * 4 + (threadIdx.x >> 6);
    const int lane = threadIdx.x & 63;
    if (e >= ENUM) return;
    const int f0 = lane * 2;
    const float2 v = *(const float2*)(Eres + (size_t)e * 128 + f0);
    const float4 a0 = *(const float4*)(A2 + f0 * 4);
    const float4 a1 = *(const float4*)(A2 + f0 * 4 + 4);
    float s0 = v.x * a0.x + v.y * a1.x;
    float s1 = v.x * a0.y + v.y * a1.y;
    float s2 = v.x * a0.z + v.y * a1.z;
    float s3 = v.x * a0.w + v.y * a1.w;
    #pragma unroll
    for (int off = 1; off < 64; off <<= 1) {
        s0 += __shfl_xor(s0, off); s1 += __shfl_xor(s1, off);
        s2 += __shfl_xor(s2, off); s3 += __shfl_xor(s3, off);
    }
    if (lane == 0) *(float4*)(ae + (size_t)e * 4) = make_float4(s0, s1, s2, s3);
}

// -------- CSR build --------
__global__ __launch_bounds__(256) void hist_k(
    const int* __restrict__ row, int* __restrict__ cnt)
{
    const int k = blockIdx.x * 256 + threadIdx.x;
    if (k < NNZ_C) atomicAdd(cnt + row[k], 1);
}

__global__ __launch_bounds__(256) void scan1_k(
    const int* __restrict__ cnt, int* __restrict__ rp, int* __restrict__ bsum, int n)
{
    __shared__ int sh[256];
    const int t = threadIdx.x, g = blockIdx.x * 256 + t;
    const int v = (g < n) ? cnt[g] : 0;
    sh[t] = v; __syncthreads();
    #pragma unroll
    for (int off = 1; off < 256; off <<= 1) {
        const int add = (t >= off) ? sh[t - off] : 0;
        __syncthreads();
        sh[t] += add;
        __syncthreads();
    }
    if (g < n) rp[g] = sh[t] - v;
    if (t == 255) bsum[blockIdx.x] = sh[255];
}

__global__ __launch_bounds__(512) void scan2_k(int* __restrict__ bsum, int nb)
{
    __shared__ int sh[512];
    const int t = threadIdx.x;
    const int v = (t < nb) ? bsum[t] : 0;
    sh[t] = v; __syncthreads();
    #pragma unroll
    for (int off = 1; off < 512; off <<= 1) {
        const int add = (t >= off) ? sh[t - off] : 0;
        __syncthreads();
        sh[t] += add;
        __syncthreads();
    }
    if (t < nb) bsum[t] = sh[t] - v;
}

__global__ __launch_bounds__(256) void scan3_k(
    int* __restrict__ rp, const int* __restrict__ bsum, int* __restrict__ cur, int n)
{
    const int g = blockIdx.x * 256 + threadIdx.x;
    if (g < n) {
        const int v = rp[g] + bsum[g >> 8];
        rp[g] = v;
        cur[g] = v;
    }
    if (g == 0) rp[n] = NNZ_C;
}

__global__ __launch_bounds__(256) void fill_k(
    const int* __restrict__ row, int* __restrict__ cur, int* __restrict__ eidx)
{
    const int k = blockIdx.x * 256 + threadIdx.x;
    if (k < NNZ_C) {
        const int p = atomicAdd(cur + row[k], 1);
        eidx[p] = k;
    }
}

// -------- CSR softmax: one thread per row; alphag PRE-SCALED by 0.25/Dn --------
__global__ __launch_bounds__(256) void softmax_csr_k(
    const int* __restrict__ rowptr, const int* __restrict__ eidx,
    const float* __restrict__ adjv, const float* __restrict__ ax,
    const float* __restrict__ ae, float* __restrict__ alpha,
    float* __restrict__ alphag)
{
    const int r = blockIdx.x * 256 + threadIdx.x;
    if (r >= NN) return;
    const int p0 = rowptr[r], p1 = rowptr[r + 1];
    if (p0 == p1) return;
    const float4 axv = *(const float4*)(ax + (size_t)r * 4);

#define LRELU4(a) { a.x = (a.x >= 0.f) ? a.x : 0.2f * a.x;                    \
                    a.y = (a.y >= 0.f) ? a.y : 0.2f * a.y;                    \
                    a.z = (a.z >= 0.f) ? a.z : 0.2f * a.z;                    \
                    a.w = (a.w >= 0.f) ? a.w : 0.2f * a.w; }

    float ds = 0.f;
    float4 m = make_float4(-1e30f, -1e30f, -1e30f, -1e30f);
    for (int p = p0; p < p1; ++p) {
        const int c = eidx[p] % ENUM;
        ds += adjv[c];
        float4 a = *(const float4*)(ae + (size_t)c * 4);
        a.x += axv.x; a.y += axv.y; a.z += axv.z; a.w += axv.w;
        LRELU4(a);
        m.x = fmaxf(m.x, a.x); m.y = fmaxf(m.y, a.y);
        m.z = fmaxf(m.z, a.z); m.w = fmaxf(m.w, a.w);
    }
    float4 s = make_float4(0.f, 0.f, 0.f, 0.f);
    for (int p = p0; p < p1; ++p) {
        const int c = eidx[p] % ENUM;
        float4 a = *(const float4*)(ae + (size_t)c * 4);
        a.x += axv.x; a.y += axv.y; a.z += axv.z; a.w += axv.w;
        LRELU4(a);
        s.x += __expf(a.x - m.x); s.y += __expf(a.y - m.y);
        s.z += __expf(a.z - m.z); s.w += __expf(a.w - m.w);
    }
    const float4 rs = make_float4(1.f / s.x, 1.f / s.y, 1.f / s.z, 1.f / s.w);
    const float w = 0.25f / ds;
    for (int p = p0; p < p1; ++p) {
        const int k = eidx[p];
        const int c = k % ENUM;
        float4 a = *(const float4*)(ae + (size_t)c * 4);
        a.x += axv.x; a.y += axv.y; a.z += axv.z; a.w += axv.w;
        LRELU4(a);
        float4 v;
        v.x = __expf(a.x - m.x) * rs.x; v.y = __expf(a.y - m.y) * rs.y;
        v.z = __expf(a.z - m.z) * rs.z; v.w = __expf(a.w - m.w) * rs.w;
        *(float4*)(alpha + ((size_t)k << 2)) = v;
        float4 vg;
        vg.x = v.x * w; vg.y = v.y * w; vg.z = v.z * w; vg.w = v.w * w;
        *(float4*)(alphag + ((size_t)p << 2)) = vg;
    }
#undef LRELU4
}

// -------- aggX[e][h][d] = (1/8) sum_j alpha[k,h] * X[row[k],d]  (bf16) ----
__global__ __launch_bounds__(256) void aggx_k(
    const int* __restrict__ row, const float* __restrict__ alpha,
    const float* __restrict__ X, unsigned short* __restrict__ aggX)
{
    const int e = blockIdx.x * 4 + (threadIdx.x >> 6);
    const int lane = threadIdx.x & 63;
    if (e >= ENUM) return;
    const int d0 = lane * 2;
    float h0a = 0.f, h0b = 0.f, h1a = 0.f, h1b = 0.f;
    float h2a = 0.f, h2b = 0.f, h3a = 0.f, h3b = 0.f;
    #pragma unroll
    for (int j = 0; j < 8; j++) {
        const int k = e + j * ENUM;
        const float4 al = *(const float4*)(alpha + ((size_t)k << 2));
        const float2 x = *(const float2*)(X + (size_t)row[k] * 128 + d0);
        h0a += al.x * x.x; h0b += al.x * x.y;
        h1a += al.y * x.x; h1b += al.y * x.y;
        h2a += al.z * x.x; h2b += al.z * x.y;
        h3a += al.w * x.x; h3b += al.w * x.y;
    }
    unsigned* dst = (unsigned*)aggX + (size_t)e * 256 + lane;
    dst[0]   = pack2(0.125f * h0a, 0.125f * h0b);
    dst[64]  = pack2(0.125f * h1a, 0.125f * h1b);
    dst[128] = pack2(0.125f * h2a, 0.125f * h2b);
    dst[192] = pack2(0.125f * h3a, 0.125f * h3b);
}

// -------- out_e[e][h][f] = aggX[e][h][:] @ Wlin_h  (per-head K=128 MFMA GEMM) ----
__global__ __launch_bounds__(256) void gemmoe_k(
    const unsigned short* __restrict__ aggX, const unsigned short* __restrict__ WlinhT,
    unsigned short* __restrict__ out_e, int M)
{
    __shared__ unsigned short As[64 * 128];
    __shared__ unsigned short Bs[128 * 128];
    const int tid = threadIdx.x;
    const int r0 = blockIdx.x * 64;
    const int lane = tid & 63;
    const int w = tid >> 6;
    const int wr = w >> 1, wc = w & 1;   // wave: rows wr*32..+31, cols wc*64..+63
    const int fr = lane & 15;
    const int kg = (lane >> 4) * 8;

    for (int h = 0; h < 4; h++) {
        __syncthreads();   // prior As/Bs reads complete
        {
            int rr = tid >> 4;
            const int kc = (tid & 15) * 8;
            #pragma unroll
            for (int it = 0; it < 4; it++) {
                int r = r0 + rr; if (r > M - 1) r = M - 1;
                const uint4 va = *(const uint4*)(aggX + (size_t)r * 512 + h * 128 + kc);
                *(uint4*)&As[(rr * 128 + kc) ^ ((rr & 7) << 3)] = va;
                rr += 16;
            }
        }
        {
            const unsigned short* src = WlinhT + (size_t)h * 16384 + tid * 8;
            unsigned short* dst = &Bs[tid * 8];
            #pragma unroll
            for (int it = 0; it < 8; it++)
                gload_lds16(src + it * 2048, dst + it * 2048);
        }
        __syncthreads();

        f32x4 acc[2][4] = {};
        #pragma unroll
        for (int ks = 0; ks < 4; ks++) {
            bf16x8 a[2], b[4];
            #pragma unroll
            for (int m = 0; m < 2; m++) {
                const int ar = wr * 32 + m * 16 + fr;
                a[m] = *(const bf16x8*)&As[(ar * 128 + ks * 32 + kg) ^ ((ar & 7) << 3)];
            }
            #pragma unroll
            for (int n = 0; n < 4; n++) {
                const int br = wc * 64 + n * 16 + fr;
                b[n] = *(const bf16x8*)&Bs[(br * 128 + ks * 32 + kg) ^ ((br & 7) << 3)];
            }
            #pragma unroll
            for (int m = 0; m < 2; m++)
                #pragma unroll
                for (int n = 0; n < 4; n++)
                    acc[m][n] = __builtin_amdgcn_mfma_f32_16x16x32_bf16(a[m], b[n], acc[m][n], 0, 0, 0);
        }

        #pragma unroll
        for (int m = 0; m < 2; m++) {
            #pragma unroll
            for (int n = 0; n < 4; n++) {
                const int c = wc * 64 + n * 16 + fr;
                #pragma unroll
                for (int j = 0; j < 4; j++) {
                    const int r = r0 + wr * 32 + m * 16 + (lane >> 4) * 4 + j;
                    if (r < M)
                        out_e[(size_t)r * 512 + h * 128 + c] = f2bf(acc[m][n][j]);
                }
            }
        }
    }
}

// -------- final CSR gather: alphag pre-scaled, no adjv --------
__global__ __launch_bounds__(256) void xgather_k(
    const int* __restrict__ rowptr, const int* __restrict__ eidx,
    const float* __restrict__ alphag, const unsigned short* __restrict__ out_e,
    const float* __restrict__ bias, float* __restrict__ Xres)
{
    const int r = blockIdx.x * 4 + (threadIdx.x >> 6);
    const int lane = threadIdx.x & 63;
    if (r >= NN) return;
    const int p0 = rowptr[r], p1 = rowptr[r + 1];
    const int f0 = lane * 2;
    float a0 = 0.f, a1 = 0.f;

#define XG_BODY(P) {                                                          \
        const int c = eidx[P] % ENUM;                                         \
        const float4 al = *(const float4*)(alphag + ((size_t)(P) << 2));      \
        const unsigned* ob = (const unsigned*)out_e + (size_t)c * 256 + lane; \
        const unsigned u0 = ob[0], u1 = ob[64], u2 = ob[128], u3 = ob[192];   \
        a0 += al.x * blo(u0) + al.y * blo(u1) + al.z * blo(u2) + al.w * blo(u3); \
        a1 += al.x * bhi(u0) + al.y * bhi(u1) + al.z * bhi(u2) + al.w * bhi(u3); \
    }

    int p = p0;
    for (; p + 2 <= p1; p += 2) { XG_BODY(p); XG_BODY(p + 1); }
    if (p < p1) XG_BODY(p);
#undef XG_BODY

    float2 o;
    o.x = bias[f0] + a0;
    o.y = bias[f0 + 1] + a1;
    *(float2*)(Xres + (size_t)r * 128 + f0) = o;
}

extern "C" void kernel_launch(void* const* d_in, const int* in_sizes, int n_in,
                              void* d_out, int out_size, void* d_ws, size_t ws_size,
                              hipStream_t stream)
{
    const float* X         = (const float*)d_in[0];
    const float* E         = (const float*)d_in[1];
    const int*   adj       = (const int*)d_in[2];
    const float* adjv      = (const float*)d_in[3];
    const float* Wn        = (const float*)d_in[4];
    const float* bn        = (const float*)d_in[5];
    const float* We        = (const float*)d_in[6];
    const float* be        = (const float*)d_in[7];
    const float* Wlin      = (const float*)d_in[8];
    const float* att       = (const float*)d_in[9];
    const float* bias_conv = (const float*)d_in[10];
    const int* row = adj;

    float* Xres = (float*)d_out;
    float* Eres = Xres + (size_t)NN * 128;

    // workspace layout (~68 MB)
    char* wsb = (char*)d_ws;
    unsigned short* aggX  = (unsigned short*)(wsb);              // 25.6 MB
    unsigned short* out_e = (unsigned short*)(wsb + 25600000);   // 25.6 MB
    unsigned short* agg   = (unsigned short*)(wsb + 51200000);   // 6.5 MB
    unsigned short* WlinhT= (unsigned short*)(wsb + 57800000);   // 128 KB (per-head, swz)
    unsigned short* WnT   = (unsigned short*)(wsb + 57931072);   // 32 KB (swz)
    unsigned short* WeT   = (unsigned short*)(wsb + 57963840);   // 32 KB (swz)
    float* A1    = (float*)(wsb + 57996608);                     // 2 KB
    float* A2    = (float*)(wsb + 57998656);                     // 2 KB
    float* bnbe  = (float*)(wsb + 58000704);                     // 512 B (rsv 2 KB)
    float* ax    = (float*)(wsb + 58002752);                     // 1.6 MB
    float* ae    = (float*)(wsb + 59602752);                     // 0.4 MB
    float* alpha = (float*)(wsb + 60002752);                     // 3.2 MB
    int* rowptr  = (int*)(wsb + 63202752);                       // 400,016 B
    int* cnt     = (int*)(wsb + 63602768);                       // 400,000 B
    int* eidx    = (int*)(wsb + 64002768);                       // 800,000 B
    int* bsum    = (int*)(wsb + 64802768);                       // 2 KB
    float* alphag= (float*)(wsb + 64804816);                     // 3.2 MB

    // ---- fused prep (weights + attw + zero cnt) ----
    prep_k<<<385 + (NN + 255) / 256, 256, 0, stream>>>(
        Wlin, Wn, We, att, bn, be, WlinhT, WnT, WeT, A1, A2, bnbe, cnt);

    // ---- CSR build ----
    hist_k<<<(NNZ_C + 255) / 256, 256, 0, stream>>>(row, cnt);
    scan1_k<<<(NN + 255) / 256, 256, 0, stream>>>(cnt, rowptr, bsum, NN);
    scan2_k<<<1, 512, 0, stream>>>(bsum, (NN + 255) / 256);
    scan3_k<<<(NN + 255) / 256, 256, 0, stream>>>(rowptr, bsum, cnt, NN);
    fill_k<<<(NNZ_C + 255) / 256, 256, 0, stream>>>(row, cnt, eidx);

    // ---- attention logits ----
    ax_k<<<NN / 4, 256, 0, stream>>>(X, A1, ax, NN);

    // ---- E path: agg -> combined GEMM -> ae ----
    agg_k<<<ENUM / 4, 256, 0, stream>>>(row, adjv, X, agg);
    gemme_k<<<391, 256, 0, stream>>>(agg, E, WnT, WeT, bnbe, Eres, ENUM);
    ae_k<<<ENUM / 4, 256, 0, stream>>>(Eres, A2, ae);

    // ---- CSR softmax (alphag pre-scaled by 0.25/Dn) ----
    softmax_csr_k<<<(NN + 255) / 256, 256, 0, stream>>>(
        rowptr, eidx, adjv, ax, ae, alpha, alphag);

    // ---- node -> hyperedge aggregation (pre-transform) ----
    aggx_k<<<ENUM / 4, 256, 0, stream>>>(row, alpha, X, aggX);

    // ---- per-head transform: out_e = aggX @ Wlin_h ----
    gemmoe_k<<<(ENUM + 63) / 64, 256, 0, stream>>>(aggX, WlinhT, out_e, ENUM);

    // ---- hyperedge -> node: CSR gather ----
    xgather_k<<<NN / 4, 256, 0, stream>>>(rowptr, eidx, alphag, out_e, bias_conv, Xres);
}

// Round 20
// 204.402 us; speedup vs baseline: 1.2553x; 1.0048x over previous
//
#include <hip/hip_runtime.h>

#define NN 100000
#define ENUM 25000
#define NNZ_C 200000
// D = 128, H = 4, F = 128, Wlin: [128,512]
// Transform-after-first-aggregation:
//   aggX[e][h][d] = (1/8) sum_k alpha[k,h] Xbf[row_k,d]      (bf16, [EN][4][128])
//   out_e[e][h][f] = aggX[e][h][:] @ Wlin_h                  (dense per-head GEMM)
//   Xres[r] = sum_p sum_h alphag[p,h]*out_e[c_p][h][:] + bias   (alphag pre-scaled by 0.25/Dn)
// E-path: agg = B^-1 A^T Xbf ; Eres = agg@Wn + E@We + (bn+be) + E.
// X converted ONCE to bf16 (Xbf) -> all random row-gathers move 256B not 512B.
// Weights PRE-SWIZZLED in global (pos ^ ((row&7)<<3)) -> linear global_load_lds DMA.

typedef __attribute__((ext_vector_type(8))) short bf16x8;
typedef __attribute__((ext_vector_type(4))) float f32x4;

__device__ __forceinline__ float blo(unsigned u) { return __uint_as_float(u << 16); }
__device__ __forceinline__ float bhi(unsigned u) { return __uint_as_float(u & 0xFFFF0000u); }
__device__ __forceinline__ unsigned short f2bf(float x) {
    unsigned u = __float_as_uint(x);
    unsigned r = (u + 0x7fff + ((u >> 16) & 1)) >> 16;   // RNE
    return (unsigned short)r;
}
__device__ __forceinline__ unsigned pack2(float a, float b) {
    return (unsigned)f2bf(a) | ((unsigned)f2bf(b) << 16);
}
__device__ __forceinline__ void gload_lds16(const unsigned short* g, unsigned short* l) {
    __builtin_amdgcn_global_load_lds(
        (const __attribute__((address_space(1))) void*)g,
        (__attribute__((address_space(3))) void*)l, 16, 0, 0);
}

// ---- fused prep: WlinhT (256) | WnT (64) | WeT (64) | attw (1) | zero cnt (391) | Xbf (12500) ----
__global__ __launch_bounds__(256) void prep_k(
    const float* __restrict__ Wlin, const float* __restrict__ Wn,
    const float* __restrict__ We, const float* __restrict__ att,
    const float* __restrict__ bn, const float* __restrict__ be,
    const float* __restrict__ X,
    unsigned short* __restrict__ WlinhT, unsigned short* __restrict__ WnT,
    unsigned short* __restrict__ WeT, float* __restrict__ A1,
    float* __restrict__ A2, float* __restrict__ bnbe, int* __restrict__ cnt,
    unsigned short* __restrict__ Xbf)
{
    const int bid = blockIdx.x;
    if (bid < 256) {
        // WlinhT[h][f][d] = Wlin[d][h*128+f], swizzled
        const int t = bid * 256 + threadIdx.x;
        const int d = t >> 9, c512 = t & 511;
        const int h = c512 >> 7, f = c512 & 127;
        const size_t pos = (size_t)h * 16384 + (((size_t)f * 128 + d) ^ ((f & 7) << 3));
        WlinhT[pos] = f2bf(Wlin[t]);
    } else if (bid < 320) {
        const int t = (bid - 256) * 256 + threadIdx.x;
        const int c = t & 127, k = t >> 7;
        WnT[(((size_t)c * 128 + k) ^ ((c & 7) << 3))] = f2bf(Wn[t]);
    } else if (bid < 384) {
        const int t = (bid - 320) * 256 + threadIdx.x;
        const int c = t & 127, k = t >> 7;
        WeT[(((size_t)c * 128 + k) ^ ((c & 7) << 3))] = f2bf(We[t]);
    } else if (bid == 384) {
        const int t = threadIdx.x;
        const int k = t & 127;
        const int pair = t >> 7;
        const float* wrow = Wlin + (size_t)k * 512;
        float s[4];
        #pragma unroll
        for (int h = 0; h < 4; h++) {
            float acc = 0.f;
            const float* ap = att + h * 256 + pair * 128;
            const float* wp = wrow + h * 128;
            for (int f = 0; f < 128; f++) acc += wp[f] * ap[f];
            s[h] = acc;
        }
        float* dst = (pair ? A2 : A1) + k * 4;
        dst[0] = s[0]; dst[1] = s[1]; dst[2] = s[2]; dst[3] = s[3];
        if (t < 128) bnbe[t] = bn[t] + be[t];
    } else if (bid < 776) {
        const int t = (bid - 385) * 256 + threadIdx.x;
        if (t < NN) cnt[t] = 0;
    } else {
        // Xbf: 4 f32 -> 4 bf16 per thread
        const int t = (bid - 776) * 256 + threadIdx.x;
        if (t < NN * 32) {
            const float4 a = ((const float4*)X)[t];
            ushort4 u;
            u.x = f2bf(a.x); u.y = f2bf(a.y); u.z = f2bf(a.z); u.w = f2bf(a.w);
            ((ushort4*)Xbf)[t] = u;
        }
    }
}

// -------- ax[r,h] = Xbf[r,:] @ A1[:,h]  (one wave per row) --------
__global__ __launch_bounds__(256) void ax_k(
    const unsigned short* __restrict__ Xbf, const float* __restrict__ A1,
    float* __restrict__ ax, int M)
{
    const int r = blockIdx.x * 4 + (threadIdx.x >> 6);
    const int lane = threadIdx.x & 63;
    if (r >= M) return;
    const int f0 = lane * 2;
    const unsigned u = ((const unsigned*)Xbf)[(size_t)r * 64 + lane];
    const float xa = blo(u), xb = bhi(u);
    const float4 a0 = *(const float4*)(A1 + f0 * 4);
    const float4 a1 = *(const float4*)(A1 + f0 * 4 + 4);
    float s0 = xa * a0.x + xb * a1.x;
    float s1 = xa * a0.y + xb * a1.y;
    float s2 = xa * a0.z + xb * a1.z;
    float s3 = xa * a0.w + xb * a1.w;
    #pragma unroll
    for (int off = 1; off < 64; off <<= 1) {
        s0 += __shfl_xor(s0, off); s1 += __shfl_xor(s1, off);
        s2 += __shfl_xor(s2, off); s3 += __shfl_xor(s3, off);
    }
    if (lane == 0) *(float4*)(ax + (size_t)r * 4) = make_float4(s0, s1, s2, s3);
}

// -------- agg[e] = (1/deg) sum_j w * Xbf[row[k]]  (bf16 out, E-path) --------
__global__ __launch_bounds__(256) void agg_k(
    const int* __restrict__ row, const float* __restrict__ adjv,
    const unsigned short* __restrict__ Xbf, unsigned short* __restrict__ agg)
{
    const int e = blockIdx.x * 4 + (threadIdx.x >> 6);
    const int lane = threadIdx.x & 63;
    if (e >= ENUM) return;
    float a0 = 0.f, a1 = 0.f, deg = 0.f;
    #pragma unroll
    for (int j = 0; j < 8; j++) {
        const int k = e + j * ENUM;
        const float w = adjv[k];
        deg += w;
        const unsigned u = ((const unsigned*)Xbf)[(size_t)row[k] * 64 + lane];
        a0 += w * blo(u); a1 += w * bhi(u);
    }
    const float rs = 1.f / deg;
    ((unsigned*)agg)[(size_t)e * 64 + lane] = pack2(a0 * rs, a1 * rs);
}

// ---- combined E GEMM: Eres = agg@Wn + E@We + bnbe + E  (f32 out) ----
__global__ __launch_bounds__(256) void gemme_k(
    const unsigned short* __restrict__ agg, const float* __restrict__ E,
    const unsigned short* __restrict__ WnT, const unsigned short* __restrict__ WeT,
    const float* __restrict__ bnbe, float* __restrict__ Eres, int M)
{
    __shared__ unsigned short Ag[64 * 128];
    __shared__ unsigned short Ae[64 * 128];
    __shared__ unsigned short Bw[64 * 128];
    __shared__ unsigned short Bv[64 * 128];
    const int tid = threadIdx.x;
    const int r0 = blockIdx.x * 64;

    {
        int rr = tid >> 4;
        const int kc = (tid & 15) * 8;
        #pragma unroll
        for (int it = 0; it < 4; it++) {
            int r = r0 + rr; if (r > M - 1) r = M - 1;
            const uint4 vg = *(const uint4*)(agg + (size_t)r * 128 + kc);
            const float* ep = E + (size_t)r * 128 + kc;
            const float4 f0 = *(const float4*)ep;
            const float4 f1 = *(const float4*)(ep + 4);
            uint4 ve;
            ve.x = pack2(f0.x, f0.y); ve.y = pack2(f0.z, f0.w);
            ve.z = pack2(f1.x, f1.y); ve.w = pack2(f1.z, f1.w);
            const int idx = (rr * 128 + kc) ^ ((rr & 7) << 3);
            *(uint4*)&Ag[idx] = vg;
            *(uint4*)&Ae[idx] = ve;
            rr += 16;
        }
    }
    __syncthreads();

    const int lane = tid & 63;
    const int wid = tid >> 6;
    const int wr = wid >> 1, wc = wid & 1;
    const int fr = lane & 15;
    const int kg = (lane >> 4) * 8;

    bf16x8 ag[2][4], ae_[2][4];
    #pragma unroll
    for (int m = 0; m < 2; m++) {
        const int ar = wr * 32 + m * 16 + fr;
        #pragma unroll
        for (int ks = 0; ks < 4; ks++) {
            const int idx = (ar * 128 + ks * 32 + kg) ^ ((ar & 7) << 3);
            ag[m][ks] = *(const bf16x8*)&Ag[idx];
            ae_[m][ks] = *(const bf16x8*)&Ae[idx];
        }
    }

    for (int ct = 0; ct < 2; ct++) {
        __syncthreads();
        {
            const unsigned short* s1 = WnT + (size_t)ct * 8192 + tid * 8;
            const unsigned short* s2 = WeT + (size_t)ct * 8192 + tid * 8;
            unsigned short* d1 = &Bw[tid * 8];
            unsigned short* d2 = &Bv[tid * 8];
            #pragma unroll
            for (int it = 0; it < 4; it++) {
                gload_lds16(s1 + it * 2048, d1 + it * 2048);
                gload_lds16(s2 + it * 2048, d2 + it * 2048);
            }
        }
        __syncthreads();

        f32x4 acc[2][2] = {};
        #pragma unroll
        for (int ks = 0; ks < 4; ks++) {
            bf16x8 bw[2], bv[2];
            #pragma unroll
            for (int n = 0; n < 2; n++) {
                const int br = wc * 32 + n * 16 + fr;
                const int idx = (br * 128 + ks * 32 + kg) ^ ((br & 7) << 3);
                bw[n] = *(const bf16x8*)&Bw[idx];
                bv[n] = *(const bf16x8*)&Bv[idx];
            }
            #pragma unroll
            for (int m = 0; m < 2; m++)
                #pragma unroll
                for (int n = 0; n < 2; n++) {
                    acc[m][n] = __builtin_amdgcn_mfma_f32_16x16x32_bf16(ag[m][ks], bw[n], acc[m][n], 0, 0, 0);
                    acc[m][n] = __builtin_amdgcn_mfma_f32_16x16x32_bf16(ae_[m][ks], bv[n], acc[m][n], 0, 0, 0);
                }
        }

        #pragma unroll
        for (int m = 0; m < 2; m++) {
            #pragma unroll
            for (int n = 0; n < 2; n++) {
                const int c = ct * 64 + wc * 32 + n * 16 + fr;
                #pragma unroll
                for (int j = 0; j < 4; j++) {
                    const int r = r0 + wr * 32 + m * 16 + (lane >> 4) * 4 + j;
                    if (r < M)
                        Eres[(size_t)r * 128 + c] = acc[m][n][j] + bnbe[c] + E[(size_t)r * 128 + c];
                }
            }
        }
    }
}

// -------- ae[e,h] = Eres[e,:] . A2[:,h] --------
__global__ __launch_bounds__(256) void ae_k(
    const float* __restrict__ Eres, const float* __restrict__ A2,
    float* __restrict__ ae)
{
    const int e = blockIdx.x * 4 + (threadIdx.x >> 6);
    const int lane = threadIdx.x & 63;
    if (e >= ENUM) return;
    const int f0 = lane * 2;
    const float2 v = *(const float2*)(Eres + (size_t)e * 128 + f0);
    const float4 a0 = *(const float4*)(A2 + f0 * 4);
    const float4 a1 = *(const float4*)(A2 + f0 * 4 + 4);
    float s0 = v.x * a0.x + v.y * a1.x;
    float s1 = v.x * a0.y + v.y * a1.y;
    float s2 = v.x * a0.z + v.y * a1.z;
    float s3 = v.x * a0.w + v.y * a1.w;
    #pragma unroll
    for (int off = 1; off < 64; off <<= 1) {
        s0 += __shfl_xor(s0, off); s1 += __shfl_xor(s1, off);
        s2 += __shfl_xor(s2, off); s3 += __shfl_xor(s3, off);
    }
    if (lane == 0) *(float4*)(ae + (size_t)e * 4) = make_float4(s0, s1, s2, s3);
}

// -------- CSR build --------
__global__ __launch_bounds__(256) void hist_k(
    const int* __restrict__ row, int* __restrict__ cnt)
{
    const int k = blockIdx.x * 256 + threadIdx.x;
    if (k < NNZ_C) atomicAdd(cnt + row[k], 1);
}

__global__ __launch_bounds__(256) void scan1_k(
    const int* __restrict__ cnt, int* __restrict__ rp, int* __restrict__ bsum, int n)
{
    __shared__ int sh[256];
    const int t = threadIdx.x, g = blockIdx.x * 256 + t;
    const int v = (g < n) ? cnt[g] : 0;
    sh[t] = v; __syncthreads();
    #pragma unroll
    for (int off = 1; off < 256; off <<= 1) {
        const int add = (t >= off) ? sh[t - off] : 0;
        __syncthreads();
        sh[t] += add;
        __syncthreads();
    }
    if (g < n) rp[g] = sh[t] - v;
    if (t == 255) bsum[blockIdx.x] = sh[255];
}

__global__ __launch_bounds__(512) void scan2_k(int* __restrict__ bsum, int nb)
{
    __shared__ int sh[512];
    const int t = threadIdx.x;
    const int v = (t < nb) ? bsum[t] : 0;
    sh[t] = v; __syncthreads();
    #pragma unroll
    for (int off = 1; off < 512; off <<= 1) {
        const int add = (t >= off) ? sh[t - off] : 0;
        __syncthreads();
        sh[t] += add;
        __syncthreads();
    }
    if (t < nb) bsum[t] = sh[t] - v;
}

__global__ __launch_bounds__(256) void scan3_k(
    int* __restrict__ rp, const int* __restrict__ bsum, int* __restrict__ cur, int n)
{
    const int g = blockIdx.x * 256 + threadIdx.x;
    if (g < n) {
        const int v = rp[g] + bsum[g >> 8];
        rp[g] = v;
        cur[g] = v;
    }
    if (g == 0) rp[n] = NNZ_C;
}

__global__ __launch_bounds__(256) void fill_k(
    const int* __restrict__ row, int* __restrict__ cur, int* __restrict__ eidx)
{
    const int k = blockIdx.x * 256 + threadIdx.x;
    if (k < NNZ_C) {
        const int p = atomicAdd(cur + row[k], 1);
        eidx[p] = k;
    }
}

// -------- CSR softmax: one thread per row; alphag PRE-SCALED by 0.25/Dn --------
__global__ __launch_bounds__(256) void softmax_csr_k(
    const int* __restrict__ rowptr, const int* __restrict__ eidx,
    const float* __restrict__ adjv, const float* __restrict__ ax,
    const float* __restrict__ ae, float* __restrict__ alpha,
    float* __restrict__ alphag)
{
    const int r = blockIdx.x * 256 + threadIdx.x;
    if (r >= NN) return;
    const int p0 = rowptr[r], p1 = rowptr[r + 1];
    if (p0 == p1) return;
    const float4 axv = *(const float4*)(ax + (size_t)r * 4);

#define LRELU4(a) { a.x = (a.x >= 0.f) ? a.x : 0.2f * a.x;                    \
                    a.y = (a.y >= 0.f) ? a.y : 0.2f * a.y;                    \
                    a.z = (a.z >= 0.f) ? a.z : 0.2f * a.z;                    \
                    a.w = (a.w >= 0.f) ? a.w : 0.2f * a.w; }

    float ds = 0.f;
    float4 m = make_float4(-1e30f, -1e30f, -1e30f, -1e30f);
    for (int p = p0; p < p1; ++p) {
        const int c = eidx[p] % ENUM;
        ds += adjv[c];
        float4 a = *(const float4*)(ae + (size_t)c * 4);
        a.x += axv.x; a.y += axv.y; a.z += axv.z; a.w += axv.w;
        LRELU4(a);
        m.x = fmaxf(m.x, a.x); m.y = fmaxf(m.y, a.y);
        m.z = fmaxf(m.z, a.z); m.w = fmaxf(m.w, a.w);
    }
    float4 s = make_float4(0.f, 0.f, 0.f, 0.f);
    for (int p = p0; p < p1; ++p) {
        const int c = eidx[p] % ENUM;
        float4 a = *(const float4*)(ae + (size_t)c * 4);
        a.x += axv.x; a.y += axv.y; a.z += axv.z; a.w += axv.w;
        LRELU4(a);
        s.x += __expf(a.x - m.x); s.y += __expf(a.y - m.y);
        s.z += __expf(a.z - m.z); s.w += __expf(a.w - m.w);
    }
    const float4 rs = make_float4(1.f / s.x, 1.f / s.y, 1.f / s.z, 1.f / s.w);
    const float w = 0.25f / ds;
    for (int p = p0; p < p1; ++p) {
        const int k = eidx[p];
        const int c = k % ENUM;
        float4 a = *(const float4*)(ae + (size_t)c * 4);
        a.x += axv.x; a.y += axv.y; a.z += axv.z; a.w += axv.w;
        LRELU4(a);
        float4 v;
        v.x = __expf(a.x - m.x) * rs.x; v.y = __expf(a.y - m.y) * rs.y;
        v.z = __expf(a.z - m.z) * rs.z; v.w = __expf(a.w - m.w) * rs.w;
        *(float4*)(alpha + ((size_t)k << 2)) = v;
        float4 vg;
        vg.x = v.x * w; vg.y = v.y * w; vg.z = v.z * w; vg.w = v.w * w;
        *(float4*)(alphag + ((size_t)p << 2)) = vg;
    }
#undef LRELU4
}

// -------- aggX[e][h][d] = (1/8) sum_j alpha[k,h] * Xbf[row[k],d]  (bf16) ----
__global__ __launch_bounds__(256) void aggx_k(
    const int* __restrict__ row, const float* __restrict__ alpha,
    const unsigned short* __restrict__ Xbf, unsigned short* __restrict__ aggX)
{
    const int e = blockIdx.x * 4 + (threadIdx.x >> 6);
    const int lane = threadIdx.x & 63;
    if (e >= ENUM) return;
    float h0a = 0.f, h0b = 0.f, h1a = 0.f, h1b = 0.f;
    float h2a = 0.f, h2b = 0.f, h3a = 0.f, h3b = 0.f;
    #pragma unroll
    for (int j = 0; j < 8; j++) {
        const int k = e + j * ENUM;
        const float4 al = *(const float4*)(alpha + ((size_t)k << 2));
        const unsigned u = ((const unsigned*)Xbf)[(size_t)row[k] * 64 + lane];
        const float xa = blo(u), xb = bhi(u);
        h0a += al.x * xa; h0b += al.x * xb;
        h1a += al.y * xa; h1b += al.y * xb;
        h2a += al.z * xa; h2b += al.z * xb;
        h3a += al.w * xa; h3b += al.w * xb;
    }
    unsigned* dst = (unsigned*)aggX + (size_t)e * 256 + lane;
    dst[0]   = pack2(0.125f * h0a, 0.125f * h0b);
    dst[64]  = pack2(0.125f * h1a, 0.125f * h1b);
    dst[128] = pack2(0.125f * h2a, 0.125f * h2b);
    dst[192] = pack2(0.125f * h3a, 0.125f * h3b);
}

// -------- out_e[e][h][f] = aggX[e][h][:] @ Wlin_h  (per-head K=128 MFMA GEMM) ----
__global__ __launch_bounds__(256) void gemmoe_k(
    const unsigned short* __restrict__ aggX, const unsigned short* __restrict__ WlinhT,
    unsigned short* __restrict__ out_e, int M)
{
    __shared__ unsigned short As[64 * 128];
    __shared__ unsigned short Bs[128 * 128];
    const int tid = threadIdx.x;
    const int r0 = blockIdx.x * 64;
    const int lane = tid & 63;
    const int w = tid >> 6;
    const int wr = w >> 1, wc = w & 1;   // wave: rows wr*32..+31, cols wc*64..+63
    const int fr = lane & 15;
    const int kg = (lane >> 4) * 8;

    for (int h = 0; h < 4; h++) {
        __syncthreads();   // prior As/Bs reads complete
        {
            int rr = tid >> 4;
            const int kc = (tid & 15) * 8;
            #pragma unroll
            for (int it = 0; it < 4; it++) {
                int r = r0 + rr; if (r > M - 1) r = M - 1;
                const uint4 va = *(const uint4*)(aggX + (size_t)r * 512 + h * 128 + kc);
                *(uint4*)&As[(rr * 128 + kc) ^ ((rr & 7) << 3)] = va;
                rr += 16;
            }
        }
        {
            const unsigned short* src = WlinhT + (size_t)h * 16384 + tid * 8;
            unsigned short* dst = &Bs[tid * 8];
            #pragma unroll
            for (int it = 0; it < 8; it++)
                gload_lds16(src + it * 2048, dst + it * 2048);
        }
        __syncthreads();

        f32x4 acc[2][4] = {};
        #pragma unroll
        for (int ks = 0; ks < 4; ks++) {
            bf16x8 a[2], b[4];
            #pragma unroll
            for (int m = 0; m < 2; m++) {
                const int ar = wr * 32 + m * 16 + fr;
                a[m] = *(const bf16x8*)&As[(ar * 128 + ks * 32 + kg) ^ ((ar & 7) << 3)];
            }
            #pragma unroll
            for (int n = 0; n < 4; n++) {
                const int br = wc * 64 + n * 16 + fr;
                b[n] = *(const bf16x8*)&Bs[(br * 128 + ks * 32 + kg) ^ ((br & 7) << 3)];
            }
            #pragma unroll
            for (int m = 0; m < 2; m++)
                #pragma unroll
                for (int n = 0; n < 4; n++)
                    acc[m][n] = __builtin_amdgcn_mfma_f32_16x16x32_bf16(a[m], b[n], acc[m][n], 0, 0, 0);
        }

        #pragma unroll
        for (int m = 0; m < 2; m++) {
            #pragma unroll
            for (int n = 0; n < 4; n++) {
                const int c = wc * 64 + n * 16 + fr;
                #pragma unroll
                for (int j = 0; j < 4; j++) {
                    const int r = r0 + wr * 32 + m * 16 + (lane >> 4) * 4 + j;
                    if (r < M)
                        out_e[(size_t)r * 512 + h * 128 + c] = f2bf(acc[m][n][j]);
                }
            }
        }
    }
}

// -------- final CSR gather: alphag pre-scaled, no adjv --------
__global__ __launch_bounds__(256) void xgather_k(
    const int* __restrict__ rowptr, const int* __restrict__ eidx,
    const float* __restrict__ alphag, const unsigned short* __restrict__ out_e,
    const float* __restrict__ bias, float* __restrict__ Xres)
{
    const int r = blockIdx.x * 4 + (threadIdx.x >> 6);
    const int lane = threadIdx.x & 63;
    if (r >= NN) return;
    const int p0 = rowptr[r], p1 = rowptr[r + 1];
    const int f0 = lane * 2;
    float a0 = 0.f, a1 = 0.f;

#define XG_BODY(P) {                                                          \
        const int c = eidx[P] % ENUM;                                         \
        const float4 al = *(const float4*)(alphag + ((size_t)(P) << 2));      \
        const unsigned* ob = (const unsigned*)out_e + (size_t)c * 256 + lane; \
        const unsigned u0 = ob[0], u1 = ob[64], u2 = ob[128], u3 = ob[192];   \
        a0 += al.x * blo(u0) + al.y * blo(u1) + al.z * blo(u2) + al.w * blo(u3); \
        a1 += al.x * bhi(u0) + al.y * bhi(u1) + al.z * bhi(u2) + al.w * bhi(u3); \
    }

    int p = p0;
    for (; p + 2 <= p1; p += 2) { XG_BODY(p); XG_BODY(p + 1); }
    if (p < p1) XG_BODY(p);
#undef XG_BODY

    float2 o;
    o.x = bias[f0] + a0;
    o.y = bias[f0 + 1] + a1;
    *(float2*)(Xres + (size_t)r * 128 + f0) = o;
}

extern "C" void kernel_launch(void* const* d_in, const int* in_sizes, int n_in,
                              void* d_out, int out_size, void* d_ws, size_t ws_size,
                              hipStream_t stream)
{
    const float* X         = (const float*)d_in[0];
    const float* E         = (const float*)d_in[1];
    const int*   adj       = (const int*)d_in[2];
    const float* adjv      = (const float*)d_in[3];
    const float* Wn        = (const float*)d_in[4];
    const float* bn        = (const float*)d_in[5];
    const float* We        = (const float*)d_in[6];
    const float* be        = (const float*)d_in[7];
    const float* Wlin      = (const float*)d_in[8];
    const float* att       = (const float*)d_in[9];
    const float* bias_conv = (const float*)d_in[10];
    const int* row = adj;

    float* Xres = (float*)d_out;
    float* Eres = Xres + (size_t)NN * 128;

    // workspace layout (~94 MB)
    char* wsb = (char*)d_ws;
    unsigned short* aggX  = (unsigned short*)(wsb);              // 25.6 MB
    unsigned short* out_e = (unsigned short*)(wsb + 25600000);   // 25.6 MB
    unsigned short* agg   = (unsigned short*)(wsb + 51200000);   // 6.5 MB
    unsigned short* WlinhT= (unsigned short*)(wsb + 57800000);   // 128 KB (per-head, swz)
    unsigned short* WnT   = (unsigned short*)(wsb + 57931072);   // 32 KB (swz)
    unsigned short* WeT   = (unsigned short*)(wsb + 57963840);   // 32 KB (swz)
    float* A1    = (float*)(wsb + 57996608);                     // 2 KB
    float* A2    = (float*)(wsb + 57998656);                     // 2 KB
    float* bnbe  = (float*)(wsb + 58000704);                     // 512 B (rsv 2 KB)
    float* ax    = (float*)(wsb + 58002752);                     // 1.6 MB
    float* ae    = (float*)(wsb + 59602752);                     // 0.4 MB
    float* alpha = (float*)(wsb + 60002752);                     // 3.2 MB
    int* rowptr  = (int*)(wsb + 63202752);                       // 400,016 B
    int* cnt     = (int*)(wsb + 63602768);                       // 400,000 B
    int* eidx    = (int*)(wsb + 64002768);                       // 800,000 B
    int* bsum    = (int*)(wsb + 64802768);                       // 2 KB
    float* alphag= (float*)(wsb + 64804816);                     // 3.2 MB
    unsigned short* Xbf = (unsigned short*)(wsb + 68004816);     // 25.6 MB

    // ---- fused prep (weights + attw + zero cnt + Xbf) ----
    prep_k<<<776 + (NN * 32 + 255) / 256, 256, 0, stream>>>(
        Wlin, Wn, We, att, bn, be, X, WlinhT, WnT, WeT, A1, A2, bnbe, cnt, Xbf);

    // ---- CSR build ----
    hist_k<<<(NNZ_C + 255) / 256, 256, 0, stream>>>(row, cnt);
    scan1_k<<<(NN + 255) / 256, 256, 0, stream>>>(cnt, rowptr, bsum, NN);
    scan2_k<<<1, 512, 0, stream>>>(bsum, (NN + 255) / 256);
    scan3_k<<<(NN + 255) / 256, 256, 0, stream>>>(rowptr, bsum, cnt, NN);
    fill_k<<<(NNZ_C + 255) / 256, 256, 0, stream>>>(row, cnt, eidx);

    // ---- attention logits ----
    ax_k<<<NN / 4, 256, 0, stream>>>(Xbf, A1, ax, NN);

    // ---- E path: agg -> combined GEMM -> ae ----
    agg_k<<<ENUM / 4, 256, 0, stream>>>(row, adjv, Xbf, agg);
    gemme_k<<<391, 256, 0, stream>>>(agg, E, WnT, WeT, bnbe, Eres, ENUM);
    ae_k<<<ENUM / 4, 256, 0, stream>>>(Eres, A2, ae);

    // ---- CSR softmax (alphag pre-scaled by 0.25/Dn) ----
    softmax_csr_k<<<(NN + 255) / 256, 256, 0, stream>>>(
        rowptr, eidx, adjv, ax, ae, alpha, alphag);

    // ---- node -> hyperedge aggregation (pre-transform) ----
    aggx_k<<<ENUM / 4, 256, 0, stream>>>(row, alpha, Xbf, aggX);

    // ---- per-head transform: out_e = aggX @ Wlin_h ----
    gemmoe_k<<<(ENUM + 63) / 64, 256, 0, stream>>>(aggX, WlinhT, out_e, ENUM);

    // ---- hyperedge -> node: CSR gather ----
    xgather_k<<<NN / 4, 256, 0, stream>>>(rowptr, eidx, alphag, out_e, bias_conv, Xres);
}